// Round 1
// baseline (2436.083 us; speedup 1.0000x reference)
//
#include <hip/hip_runtime.h>

#define NPG 38          // nodes per graph
#define HEAD_BLK 256    // graphs per block in head kernel

// ---------------------------------------------------------------------------
// Edge kernel: theta = ea*we + be; msg = x[src]*theta; atomicAdd(agg[dst], msg)
// 4 edges per thread via int4/float4 vector loads, grid-stride.
// ---------------------------------------------------------------------------
__global__ __launch_bounds__(256) void edge_kernel(
    const float* __restrict__ x,
    const int*   __restrict__ src,
    const int*   __restrict__ dst,
    const float* __restrict__ ea,
    const float* __restrict__ w_edge,
    const float* __restrict__ b_edge,
    float* __restrict__ agg,
    int nquads)
{
    const float we = w_edge[0];
    const float be = b_edge[0];
    int tid    = blockIdx.x * blockDim.x + threadIdx.x;
    int stride = gridDim.x * blockDim.x;
    const int4*   src4 = reinterpret_cast<const int4*>(src);
    const int4*   dst4 = reinterpret_cast<const int4*>(dst);
    const float4* ea4  = reinterpret_cast<const float4*>(ea);
    for (int q = tid; q < nquads; q += stride) {
        int4   s4 = src4[q];
        int4   d4 = dst4[q];
        float4 e4 = ea4[q];
        float m0 = x[s4.x] * fmaf(e4.x, we, be);
        float m1 = x[s4.y] * fmaf(e4.y, we, be);
        float m2 = x[s4.z] * fmaf(e4.z, we, be);
        float m3 = x[s4.w] * fmaf(e4.w, we, be);
        atomicAdd(&agg[d4.x], m0);
        atomicAdd(&agg[d4.y], m1);
        atomicAdd(&agg[d4.z], m2);
        atomicAdd(&agg[d4.w], m3);
    }
}

// ---------------------------------------------------------------------------
// Head kernel: nodes = agg + x*wr + bc; h=LReLU(nodes@W1+b1); LReLU(h@W2+b2);
// LReLU(h@W3+b3); softmax. One graph per thread, 256 graphs per block.
// nodes staged coalesced through LDS.
// ---------------------------------------------------------------------------
__global__ __launch_bounds__(HEAD_BLK) void head_kernel(
    const float* __restrict__ x,
    const float* __restrict__ agg,
    const float* __restrict__ w_root,
    const float* __restrict__ b_conv,
    const float* __restrict__ W1, const float* __restrict__ b1,
    const float* __restrict__ W2, const float* __restrict__ b2,
    const float* __restrict__ W3, const float* __restrict__ b3,
    float* __restrict__ out)
{
    __shared__ float s_nodes[HEAD_BLK * NPG];   // 38912 B
    __shared__ float s_W1[NPG * 4];
    __shared__ float s_W2[4 * 4];
    __shared__ float s_W3[4 * 12];
    __shared__ float s_b1[4];
    __shared__ float s_b2[4];
    __shared__ float s_b3[12];

    const int tid = threadIdx.x;

    if (tid < NPG * 4) s_W1[tid] = W1[tid];
    else if (tid >= 64 && tid < 64 + 16)  s_W2[tid - 64]  = W2[tid - 64];   // lanes 64..79 — wait, 152>64; use separate ranges below
    // (simple, branch-light weight staging: ranges chosen non-overlapping)
    if (tid >= 160 && tid < 176) s_W2[tid - 160] = W2[tid - 160];
    if (tid >= 176 && tid < 224) s_W3[tid - 176] = W3[tid - 176];
    if (tid >= 224 && tid < 228) s_b1[tid - 224] = b1[tid - 224];
    if (tid >= 228 && tid < 232) s_b2[tid - 228] = b2[tid - 228];
    if (tid >= 232 && tid < 244) s_b3[tid - 232] = b3[tid - 232];

    const float wr = w_root[0];
    const float bc = b_conv[0];

    const size_t ebase = (size_t)blockIdx.x * HEAD_BLK * NPG;
    #pragma unroll
    for (int i = tid; i < HEAD_BLK * NPG; i += HEAD_BLK) {
        const size_t idx = ebase + i;
        s_nodes[i] = agg[idx] + fmaf(x[idx], wr, bc);
    }
    __syncthreads();

    const float* nd = &s_nodes[tid * NPG];

    float h1[4];
    #pragma unroll
    for (int k = 0; k < 4; ++k) h1[k] = s_b1[k];
    #pragma unroll
    for (int j = 0; j < NPG; ++j) {
        const float nj = nd[j];
        #pragma unroll
        for (int k = 0; k < 4; ++k) h1[k] = fmaf(nj, s_W1[j * 4 + k], h1[k]);
    }
    #pragma unroll
    for (int k = 0; k < 4; ++k) h1[k] = h1[k] >= 0.0f ? h1[k] : 0.01f * h1[k];

    float h2[4];
    #pragma unroll
    for (int k = 0; k < 4; ++k) {
        float a = s_b2[k];
        #pragma unroll
        for (int j = 0; j < 4; ++j) a = fmaf(h1[j], s_W2[j * 4 + k], a);
        h2[k] = a >= 0.0f ? a : 0.01f * a;
    }

    float h3[12];
    #pragma unroll
    for (int k = 0; k < 12; ++k) {
        float a = s_b3[k];
        #pragma unroll
        for (int j = 0; j < 4; ++j) a = fmaf(h2[j], s_W3[j * 12 + k], a);
        h3[k] = a >= 0.0f ? a : 0.01f * a;
    }

    float m = h3[0];
    #pragma unroll
    for (int k = 1; k < 12; ++k) m = fmaxf(m, h3[k]);
    float sum = 0.0f;
    #pragma unroll
    for (int k = 0; k < 12; ++k) { h3[k] = expf(h3[k] - m); sum += h3[k]; }
    const float inv = 1.0f / sum;

    float4* o = reinterpret_cast<float4*>(out + (((size_t)blockIdx.x * HEAD_BLK + tid) * 12));
    o[0] = make_float4(h3[0] * inv, h3[1] * inv, h3[2]  * inv, h3[3]  * inv);
    o[1] = make_float4(h3[4] * inv, h3[5] * inv, h3[6]  * inv, h3[7]  * inv);
    o[2] = make_float4(h3[8] * inv, h3[9] * inv, h3[10] * inv, h3[11] * inv);
}

extern "C" void kernel_launch(void* const* d_in, const int* in_sizes, int n_in,
                              void* d_out, int out_size, void* d_ws, size_t ws_size,
                              hipStream_t stream)
{
    const float* x       = (const float*)d_in[0];
    const int*   eidx    = (const int*)  d_in[1];
    const float* ea      = (const float*)d_in[2];
    const float* w_edge  = (const float*)d_in[3];
    const float* b_edge  = (const float*)d_in[4];
    const float* w_root  = (const float*)d_in[5];
    const float* b_conv  = (const float*)d_in[6];
    const float* W1      = (const float*)d_in[7];
    const float* b1      = (const float*)d_in[8];
    const float* W2      = (const float*)d_in[9];
    const float* b2      = (const float*)d_in[10];
    const float* W3      = (const float*)d_in[11];
    const float* b3      = (const float*)d_in[12];
    float*       out     = (float*)d_out;

    const int N = in_sizes[0];        // total nodes
    const int E = in_sizes[2];        // total edges
    const int G = N / NPG;            // graphs

    const int* src = eidx;
    const int* dst = eidx + E;

    float* agg = (float*)d_ws;        // N floats of scratch

    // zero the aggregation buffer every call (harness poisons ws with 0xAA)
    hipMemsetAsync(agg, 0, (size_t)N * sizeof(float), stream);

    const int nquads = E / 4;         // E is divisible by 4
    const int eblocks = 2048;
    edge_kernel<<<eblocks, 256, 0, stream>>>(x, src, dst, ea, w_edge, b_edge, agg, nquads);

    const int hblocks = G / HEAD_BLK; // G = 131072 divisible by 256
    head_kernel<<<hblocks, HEAD_BLK, 0, stream>>>(x, agg, w_root, b_conv,
                                                  W1, b1, W2, b2, W3, b3, out);
}

// Round 2
// 1763.439 us; speedup vs baseline: 1.3814x; 1.3814x over previous
//
#include <hip/hip_runtime.h>

#define NPG 38
#define HEAD_BLK 256
#define SHIFT 13
#define SLICE (1 << SHIFT)        // 8192 nodes per dst-bucket (fits 32KB LDS)
#define BMAX 640                  // max buckets supported (LDS arrays)
#define NB 512                    // blocks for hist / binA (chunked edge ranges)

// ---------------------------------------------------------------------------
// K1: per-block-chunk histogram of dst buckets
// ---------------------------------------------------------------------------
__global__ __launch_bounds__(256) void k_hist(
    const int* __restrict__ dst, int nquads, int qpb, int B,
    int* __restrict__ histM)                     // [B][NB]
{
    __shared__ int h[BMAX];
    for (int i = threadIdx.x; i < B; i += 256) h[i] = 0;
    __syncthreads();
    const int blk = blockIdx.x;
    const int q0 = blk * qpb;
    const int q1 = min(q0 + qpb, nquads);
    const int4* d4 = (const int4*)dst;
    for (int q = q0 + threadIdx.x; q < q1; q += 256) {
        int4 d = d4[q];
        atomicAdd(&h[d.x >> SHIFT], 1);
        atomicAdd(&h[d.y >> SHIFT], 1);
        atomicAdd(&h[d.z >> SHIFT], 1);
        atomicAdd(&h[d.w >> SHIFT], 1);
    }
    __syncthreads();
    for (int i = threadIdx.x; i < B; i += 256) histM[i * NB + blk] = h[i];
}

// ---------------------------------------------------------------------------
// K2: per-bucket exclusive scan across blocks (in place) + totals
// ---------------------------------------------------------------------------
__global__ __launch_bounds__(256) void k_scan1(
    int* __restrict__ histM, int* __restrict__ totals)
{
    __shared__ int v[NB];
    const int b = blockIdx.x;
    for (int i = threadIdx.x; i < NB; i += 256) v[i] = histM[b * NB + i];
    __syncthreads();
    if (threadIdx.x == 0) {
        int run = 0;
        for (int i = 0; i < NB; ++i) { int t = v[i]; v[i] = run; run += t; }
        totals[b] = run;
    }
    __syncthreads();
    for (int i = threadIdx.x; i < NB; i += 256) histM[b * NB + i] = v[i];
}

// ---------------------------------------------------------------------------
// K3: exclusive scan of bucket totals -> bucket bases (single thread, B small)
// ---------------------------------------------------------------------------
__global__ void k_scan2(const int* __restrict__ totals, int* __restrict__ bbase, int B)
{
    if (threadIdx.x == 0 && blockIdx.x == 0) {
        int run = 0;
        for (int b = 0; b < B; ++b) { bbase[b] = run; run += totals[b]; }
    }
}

// ---------------------------------------------------------------------------
// K4: stream edges, gather x[src], compute msg, append (dst_local,msg) to the
// exact precomputed slot for (bucket, block). No global atomics on data.
// ---------------------------------------------------------------------------
__global__ __launch_bounds__(256) void k_binA(
    const float* __restrict__ x,
    const int* __restrict__ src, const int* __restrict__ dst,
    const float* __restrict__ ea,
    const float* __restrict__ w_edge, const float* __restrict__ b_edge,
    const int* __restrict__ histM, const int* __restrict__ bbase,
    uint2* __restrict__ pairs,
    int nquads, int qpb, int B)
{
    __shared__ int cur[BMAX];
    const int blk = blockIdx.x;
    for (int i = threadIdx.x; i < B; i += 256)
        cur[i] = bbase[i] + histM[i * NB + blk];
    __syncthreads();
    const float we = w_edge[0], be = b_edge[0];
    const int q0 = blk * qpb;
    const int q1 = min(q0 + qpb, nquads);
    const int4*   s4 = (const int4*)src;
    const int4*   d4 = (const int4*)dst;
    const float4* e4 = (const float4*)ea;
    for (int q = q0 + threadIdx.x; q < q1; q += 256) {
        int4 s = s4[q]; int4 d = d4[q]; float4 e = e4[q];
        float m0 = x[s.x] * fmaf(e.x, we, be);
        float m1 = x[s.y] * fmaf(e.y, we, be);
        float m2 = x[s.z] * fmaf(e.z, we, be);
        float m3 = x[s.w] * fmaf(e.w, we, be);
        int p0 = atomicAdd(&cur[d.x >> SHIFT], 1);
        pairs[p0] = make_uint2((unsigned)(d.x & (SLICE - 1)), __float_as_uint(m0));
        int p1 = atomicAdd(&cur[d.y >> SHIFT], 1);
        pairs[p1] = make_uint2((unsigned)(d.y & (SLICE - 1)), __float_as_uint(m1));
        int p2 = atomicAdd(&cur[d.z >> SHIFT], 1);
        pairs[p2] = make_uint2((unsigned)(d.z & (SLICE - 1)), __float_as_uint(m2));
        int p3 = atomicAdd(&cur[d.w >> SHIFT], 1);
        pairs[p3] = make_uint2((unsigned)(d.w & (SLICE - 1)), __float_as_uint(m3));
    }
}

// ---------------------------------------------------------------------------
// K5: per-bucket LDS accumulation of pairs + fused root transform -> nodes
// ---------------------------------------------------------------------------
__global__ __launch_bounds__(256) void k_binB(
    const uint2* __restrict__ pairs,
    const int* __restrict__ bbase, const int* __restrict__ totals,
    const float* __restrict__ x,
    const float* __restrict__ w_root, const float* __restrict__ b_conv,
    float* __restrict__ nodes, int N)
{
    __shared__ float slice[SLICE];
    const int b = blockIdx.x;
    for (int i = threadIdx.x; i < SLICE; i += 256) slice[i] = 0.0f;
    __syncthreads();
    const int p0 = bbase[b];
    const int p1 = p0 + totals[b];
    for (int i = p0 + threadIdx.x; i < p1; i += 256) {
        uint2 p = pairs[i];
        atomicAdd(&slice[p.x], __uint_as_float(p.y));
    }
    __syncthreads();
    const float wr = w_root[0], bc = b_conv[0];
    const int gbase = b << SHIFT;
    for (int i = threadIdx.x; i < SLICE; i += 256) {
        int gi = gbase + i;
        if (gi < N) nodes[gi] = slice[i] + fmaf(x[gi], wr, bc);
    }
}

// ---------------------------------------------------------------------------
// Fallback edge kernel (global atomics) when workspace is too small
// ---------------------------------------------------------------------------
__global__ __launch_bounds__(256) void edge_kernel_atomic(
    const float* __restrict__ x,
    const int*   __restrict__ src, const int* __restrict__ dst,
    const float* __restrict__ ea,
    const float* __restrict__ w_edge, const float* __restrict__ b_edge,
    float* __restrict__ agg, int nquads)
{
    const float we = w_edge[0], be = b_edge[0];
    int tid = blockIdx.x * blockDim.x + threadIdx.x;
    int stride = gridDim.x * blockDim.x;
    const int4*   s4 = (const int4*)src;
    const int4*   d4 = (const int4*)dst;
    const float4* e4 = (const float4*)ea;
    for (int q = tid; q < nquads; q += stride) {
        int4 s = s4[q]; int4 d = d4[q]; float4 e = e4[q];
        atomicAdd(&agg[d.x], x[s.x] * fmaf(e.x, we, be));
        atomicAdd(&agg[d.y], x[s.y] * fmaf(e.y, we, be));
        atomicAdd(&agg[d.z], x[s.z] * fmaf(e.z, we, be));
        atomicAdd(&agg[d.w], x[s.w] * fmaf(e.w, we, be));
    }
}

__global__ __launch_bounds__(256) void finalize_nodes(
    const float* __restrict__ x, const float* __restrict__ agg,
    const float* __restrict__ w_root, const float* __restrict__ b_conv,
    float* __restrict__ nodes, int N)
{
    const float wr = w_root[0], bc = b_conv[0];
    int i = blockIdx.x * blockDim.x + threadIdx.x;
    int stride = gridDim.x * blockDim.x;
    for (; i < N; i += stride) nodes[i] = agg[i] + fmaf(x[i], wr, bc);
}

// ---------------------------------------------------------------------------
// K6: head MLP over per-graph node vectors + softmax
// ---------------------------------------------------------------------------
__global__ __launch_bounds__(HEAD_BLK) void head_kernel(
    const float* __restrict__ nodes,
    const float* __restrict__ W1, const float* __restrict__ b1,
    const float* __restrict__ W2, const float* __restrict__ b2,
    const float* __restrict__ W3, const float* __restrict__ b3,
    float* __restrict__ out, int G)
{
    __shared__ float s_nodes[HEAD_BLK * NPG];   // 38912 B
    __shared__ float s_W1[NPG * 4];
    __shared__ float s_W2[4 * 4];
    __shared__ float s_W3[4 * 12];
    __shared__ float s_b1[4];
    __shared__ float s_b2[4];
    __shared__ float s_b3[12];

    const int tid = threadIdx.x;
    if (tid < NPG * 4) s_W1[tid] = W1[tid];
    if (tid >= 160 && tid < 176) s_W2[tid - 160] = W2[tid - 160];
    if (tid >= 176 && tid < 224) s_W3[tid - 176] = W3[tid - 176];
    if (tid >= 224 && tid < 228) s_b1[tid - 224] = b1[tid - 224];
    if (tid >= 228 && tid < 232) s_b2[tid - 228] = b2[tid - 228];
    if (tid >= 232 && tid < 244) s_b3[tid - 232] = b3[tid - 232];

    const int g0 = blockIdx.x * HEAD_BLK;       // first graph of this block
    const size_t ebase = (size_t)g0 * NPG;
    const int nelem = HEAD_BLK * NPG;
    const int avail = min(nelem, (G - g0) * NPG);
    for (int i = tid; i < avail; i += HEAD_BLK) s_nodes[i] = nodes[ebase + i];
    __syncthreads();

    const int g = g0 + tid;
    if (g >= G) return;
    const float* nd = &s_nodes[tid * NPG];

    float h1[4];
    #pragma unroll
    for (int k = 0; k < 4; ++k) h1[k] = s_b1[k];
    #pragma unroll
    for (int j = 0; j < NPG; ++j) {
        const float nj = nd[j];
        #pragma unroll
        for (int k = 0; k < 4; ++k) h1[k] = fmaf(nj, s_W1[j * 4 + k], h1[k]);
    }
    #pragma unroll
    for (int k = 0; k < 4; ++k) h1[k] = h1[k] >= 0.0f ? h1[k] : 0.01f * h1[k];

    float h2[4];
    #pragma unroll
    for (int k = 0; k < 4; ++k) {
        float a = s_b2[k];
        #pragma unroll
        for (int j = 0; j < 4; ++j) a = fmaf(h1[j], s_W2[j * 4 + k], a);
        h2[k] = a >= 0.0f ? a : 0.01f * a;
    }

    float h3[12];
    #pragma unroll
    for (int k = 0; k < 12; ++k) {
        float a = s_b3[k];
        #pragma unroll
        for (int j = 0; j < 4; ++j) a = fmaf(h2[j], s_W3[j * 12 + k], a);
        h3[k] = a >= 0.0f ? a : 0.01f * a;
    }

    float m = h3[0];
    #pragma unroll
    for (int k = 1; k < 12; ++k) m = fmaxf(m, h3[k]);
    float sum = 0.0f;
    #pragma unroll
    for (int k = 0; k < 12; ++k) { h3[k] = expf(h3[k] - m); sum += h3[k]; }
    const float inv = 1.0f / sum;

    float4* o = reinterpret_cast<float4*>(out + (size_t)g * 12);
    o[0] = make_float4(h3[0] * inv, h3[1] * inv, h3[2]  * inv, h3[3]  * inv);
    o[1] = make_float4(h3[4] * inv, h3[5] * inv, h3[6]  * inv, h3[7]  * inv);
    o[2] = make_float4(h3[8] * inv, h3[9] * inv, h3[10] * inv, h3[11] * inv);
}

extern "C" void kernel_launch(void* const* d_in, const int* in_sizes, int n_in,
                              void* d_out, int out_size, void* d_ws, size_t ws_size,
                              hipStream_t stream)
{
    const float* x      = (const float*)d_in[0];
    const int*   eidx   = (const int*)  d_in[1];
    const float* ea     = (const float*)d_in[2];
    const float* w_edge = (const float*)d_in[3];
    const float* b_edge = (const float*)d_in[4];
    const float* w_root = (const float*)d_in[5];
    const float* b_conv = (const float*)d_in[6];
    const float* W1 = (const float*)d_in[7];
    const float* b1 = (const float*)d_in[8];
    const float* W2 = (const float*)d_in[9];
    const float* b2 = (const float*)d_in[10];
    const float* W3 = (const float*)d_in[11];
    const float* b3 = (const float*)d_in[12];
    float* out = (float*)d_out;

    const int N = in_sizes[0];
    const int E = in_sizes[2];
    const int G = N / NPG;
    const int* src = eidx;
    const int* dst = eidx + E;
    const int nquads = E / 4;
    const int B = (N + SLICE - 1) >> SHIFT;     // 608 for this problem

    // workspace layout
    char* ws = (char*)d_ws;
    size_t off_pairs = 0;
    size_t sz_pairs  = (size_t)E * 8;
    size_t off_hist  = off_pairs + sz_pairs;
    size_t sz_hist   = (size_t)B * NB * 4;
    size_t off_tot   = off_hist + sz_hist;
    size_t off_base  = off_tot + (size_t)B * 4;
    size_t off_nodes = off_base + (size_t)B * 4;
    size_t need      = off_nodes + (size_t)N * 4;

    if (B <= BMAX && (E % 4) == 0 && need <= ws_size) {
        uint2* pairs  = (uint2*)(ws + off_pairs);
        int*   histM  = (int*)  (ws + off_hist);
        int*   totals = (int*)  (ws + off_tot);
        int*   bbase  = (int*)  (ws + off_base);
        float* nodes  = (float*)(ws + off_nodes);

        const int qpb = (nquads + NB - 1) / NB;
        k_hist <<<NB, 256, 0, stream>>>(dst, nquads, qpb, B, histM);
        k_scan1<<<B, 256, 0, stream>>>(histM, totals);
        k_scan2<<<1, 64, 0, stream>>>(totals, bbase, B);
        k_binA <<<NB, 256, 0, stream>>>(x, src, dst, ea, w_edge, b_edge,
                                        histM, bbase, pairs, nquads, qpb, B);
        k_binB <<<B, 256, 0, stream>>>(pairs, bbase, totals, x, w_root, b_conv,
                                       nodes, N);
        const int hblocks = (G + HEAD_BLK - 1) / HEAD_BLK;
        head_kernel<<<hblocks, HEAD_BLK, 0, stream>>>(nodes, W1, b1, W2, b2,
                                                      W3, b3, out, G);
    } else {
        // fallback: global-atomic scatter (needs only 2N floats of ws)
        float* agg   = (float*)d_ws;
        float* nodes = agg + N;
        hipMemsetAsync(agg, 0, (size_t)N * sizeof(float), stream);
        edge_kernel_atomic<<<2048, 256, 0, stream>>>(x, src, dst, ea, w_edge,
                                                     b_edge, agg, nquads);
        finalize_nodes<<<2048, 256, 0, stream>>>(x, agg, w_root, b_conv, nodes, N);
        const int hblocks = (G + HEAD_BLK - 1) / HEAD_BLK;
        head_kernel<<<hblocks, HEAD_BLK, 0, stream>>>(nodes, W1, b1, W2, b2,
                                                      W3, b3, out, G);
    }
}

// Round 4
// 1688.915 us; speedup vs baseline: 1.4424x; 1.0441x over previous
//
#include <hip/hip_runtime.h>

#define NPG 38
#define HEAD_BLK 256
#define SHIFT 14
#define SLICE (1 << SHIFT)        // 16384 nodes per dst-bucket (64KB LDS in k_binB)
#define BMAX 320                  // max buckets supported (LDS cursor arrays)
#define NB 2048                   // blocks for hist / binA (chunked edge ranges)
#define ETHR 512                  // threads for hist / binA

// ---------------------------------------------------------------------------
// K1: per-block-chunk histogram of dst buckets
// ---------------------------------------------------------------------------
__global__ __launch_bounds__(ETHR) void k_hist(
    const int* __restrict__ dst, int nquads, int qpb, int B,
    int* __restrict__ histM)                     // [B][NB]
{
    __shared__ int h[BMAX];
    for (int i = threadIdx.x; i < B; i += ETHR) h[i] = 0;
    __syncthreads();
    const int blk = blockIdx.x;
    const int q0 = blk * qpb;
    const int q1 = min(q0 + qpb, nquads);
    const int4* d4 = (const int4*)dst;
    for (int q = q0 + threadIdx.x; q < q1; q += ETHR) {
        int4 d = d4[q];
        atomicAdd(&h[d.x >> SHIFT], 1);
        atomicAdd(&h[d.y >> SHIFT], 1);
        atomicAdd(&h[d.z >> SHIFT], 1);
        atomicAdd(&h[d.w >> SHIFT], 1);
    }
    __syncthreads();
    for (int i = threadIdx.x; i < B; i += ETHR) histM[i * NB + blk] = h[i];
}

// ---------------------------------------------------------------------------
// K2: per-bucket exclusive scan across NB blocks (in place) + totals
// 256 threads, each scans 8 consecutive entries; 2-level scan.
// ---------------------------------------------------------------------------
__global__ __launch_bounds__(256) void k_scan1(
    int* __restrict__ histM, int* __restrict__ totals)
{
    __shared__ int v[NB];
    __shared__ int part[256];
    const int b = blockIdx.x;
    const int t = threadIdx.x;
    for (int i = t; i < NB; i += 256) v[i] = histM[b * NB + i];
    __syncthreads();
    // per-thread serial scan of its 8-chunk
    int base = t * (NB / 256);
    int run = 0;
    #pragma unroll
    for (int i = 0; i < NB / 256; ++i) { int x = v[base + i]; v[base + i] = run; run += x; }
    part[t] = run;
    __syncthreads();
    if (t == 0) {
        int r = 0;
        for (int i = 0; i < 256; ++i) { int x = part[i]; part[i] = r; r += x; }
        totals[b] = r;
    }
    __syncthreads();
    const int p = part[t];
    #pragma unroll
    for (int i = 0; i < NB / 256; ++i) v[base + i] += p;
    __syncthreads();
    for (int i = t; i < NB; i += 256) histM[b * NB + i] = v[i];
}

// ---------------------------------------------------------------------------
// K3: exclusive scan of bucket totals -> bucket bases (B small)
// ---------------------------------------------------------------------------
__global__ void k_scan2(const int* __restrict__ totals, int* __restrict__ bbase, int B)
{
    if (threadIdx.x == 0 && blockIdx.x == 0) {
        int run = 0;
        for (int b = 0; b < B; ++b) { bbase[b] = run; run += totals[b]; }
    }
}

// ---------------------------------------------------------------------------
// K4: stream edges, gather x[src], compute msg, append (dst_local,msg) to the
// exact precomputed slot for (bucket, block). No global atomics on data.
// ---------------------------------------------------------------------------
__global__ __launch_bounds__(ETHR) void k_binA(
    const float* __restrict__ x,
    const int* __restrict__ src, const int* __restrict__ dst,
    const float* __restrict__ ea,
    const float* __restrict__ w_edge, const float* __restrict__ b_edge,
    const int* __restrict__ histM, const int* __restrict__ bbase,
    uint2* __restrict__ pairs,
    int nquads, int qpb, int B)
{
    __shared__ int cur[BMAX];
    const int blk = blockIdx.x;
    for (int i = threadIdx.x; i < B; i += ETHR)
        cur[i] = bbase[i] + histM[i * NB + blk];
    __syncthreads();
    const float we = w_edge[0], be = b_edge[0];
    const int q0 = blk * qpb;
    const int q1 = min(q0 + qpb, nquads);
    const int4*   s4 = (const int4*)src;
    const int4*   d4 = (const int4*)dst;
    const float4* e4 = (const float4*)ea;
    for (int q = q0 + threadIdx.x; q < q1; q += ETHR) {
        int4 s = s4[q]; int4 d = d4[q]; float4 e = e4[q];
        float m0 = x[s.x] * fmaf(e.x, we, be);
        float m1 = x[s.y] * fmaf(e.y, we, be);
        float m2 = x[s.z] * fmaf(e.z, we, be);
        float m3 = x[s.w] * fmaf(e.w, we, be);
        int p0 = atomicAdd(&cur[d.x >> SHIFT], 1);
        pairs[p0] = make_uint2((unsigned)(d.x & (SLICE - 1)), __float_as_uint(m0));
        int p1 = atomicAdd(&cur[d.y >> SHIFT], 1);
        pairs[p1] = make_uint2((unsigned)(d.y & (SLICE - 1)), __float_as_uint(m1));
        int p2 = atomicAdd(&cur[d.z >> SHIFT], 1);
        pairs[p2] = make_uint2((unsigned)(d.z & (SLICE - 1)), __float_as_uint(m2));
        int p3 = atomicAdd(&cur[d.w >> SHIFT], 1);
        pairs[p3] = make_uint2((unsigned)(d.w & (SLICE - 1)), __float_as_uint(m3));
    }
}

// ---------------------------------------------------------------------------
// K5: per-bucket LDS accumulation of pairs + fused root transform -> nodes
// 64KB LDS slice, 1024 threads.
// ---------------------------------------------------------------------------
__global__ __launch_bounds__(1024) void k_binB(
    const uint2* __restrict__ pairs,
    const int* __restrict__ bbase, const int* __restrict__ totals,
    const float* __restrict__ x,
    const float* __restrict__ w_root, const float* __restrict__ b_conv,
    float* __restrict__ nodes, int N)
{
    __shared__ float slice[SLICE];               // 65536 B
    const int b = blockIdx.x;
    for (int i = threadIdx.x; i < SLICE; i += 1024) slice[i] = 0.0f;
    __syncthreads();
    const int p0 = bbase[b];
    const int p1 = p0 + totals[b];
    for (int i = p0 + threadIdx.x; i < p1; i += 1024) {
        uint2 p = pairs[i];
        atomicAdd(&slice[p.x], __uint_as_float(p.y));
    }
    __syncthreads();
    const float wr = w_root[0], bc = b_conv[0];
    const int gbase = b << SHIFT;
    for (int i = threadIdx.x; i < SLICE; i += 1024) {
        int gi = gbase + i;
        if (gi < N) nodes[gi] = slice[i] + fmaf(x[gi], wr, bc);
    }
}

// ---------------------------------------------------------------------------
// Fallback edge kernel (global atomics) when workspace is too small
// ---------------------------------------------------------------------------
__global__ __launch_bounds__(256) void edge_kernel_atomic(
    const float* __restrict__ x,
    const int*   __restrict__ src, const int* __restrict__ dst,
    const float* __restrict__ ea,
    const float* __restrict__ w_edge, const float* __restrict__ b_edge,
    float* __restrict__ agg, int nquads)
{
    const float we = w_edge[0], be = b_edge[0];
    int tid = blockIdx.x * blockDim.x + threadIdx.x;
    int stride = gridDim.x * blockDim.x;
    const int4*   s4 = (const int4*)src;
    const int4*   d4 = (const int4*)dst;
    const float4* e4 = (const float4*)ea;
    for (int q = tid; q < nquads; q += stride) {
        int4 s = s4[q]; int4 d = d4[q]; float4 e = e4[q];
        atomicAdd(&agg[d.x], x[s.x] * fmaf(e.x, we, be));
        atomicAdd(&agg[d.y], x[s.y] * fmaf(e.y, we, be));
        atomicAdd(&agg[d.z], x[s.z] * fmaf(e.z, we, be));
        atomicAdd(&agg[d.w], x[s.w] * fmaf(e.w, we, be));
    }
}

__global__ __launch_bounds__(256) void finalize_nodes(
    const float* __restrict__ x, const float* __restrict__ agg,
    const float* __restrict__ w_root, const float* __restrict__ b_conv,
    float* __restrict__ nodes, int N)
{
    const float wr = w_root[0], bc = b_conv[0];
    int i = blockIdx.x * blockDim.x + threadIdx.x;
    int stride = gridDim.x * blockDim.x;
    for (; i < N; i += stride) nodes[i] = agg[i] + fmaf(x[i], wr, bc);
}

// ---------------------------------------------------------------------------
// K6: head MLP over per-graph node vectors + softmax
// ---------------------------------------------------------------------------
__global__ __launch_bounds__(HEAD_BLK) void head_kernel(
    const float* __restrict__ nodes,
    const float* __restrict__ W1, const float* __restrict__ b1,
    const float* __restrict__ W2, const float* __restrict__ b2,
    const float* __restrict__ W3, const float* __restrict__ b3,
    float* __restrict__ out, int G)
{
    __shared__ float s_nodes[HEAD_BLK * NPG];   // 38912 B
    __shared__ float s_W1[NPG * 4];
    __shared__ float s_W2[4 * 4];
    __shared__ float s_W3[4 * 12];
    __shared__ float s_b1[4];
    __shared__ float s_b2[4];
    __shared__ float s_b3[12];

    const int tid = threadIdx.x;
    if (tid < NPG * 4) s_W1[tid] = W1[tid];
    if (tid >= 160 && tid < 176) s_W2[tid - 160] = W2[tid - 160];
    if (tid >= 176 && tid < 224) s_W3[tid - 176] = W3[tid - 176];
    if (tid >= 224 && tid < 228) s_b1[tid - 224] = b1[tid - 224];
    if (tid >= 228 && tid < 232) s_b2[tid - 228] = b2[tid - 228];
    if (tid >= 232 && tid < 244) s_b3[tid - 232] = b3[tid - 232];

    const int g0 = blockIdx.x * HEAD_BLK;
    const size_t ebase = (size_t)g0 * NPG;
    const int nelem = HEAD_BLK * NPG;
    const int avail = min(nelem, (G - g0) * NPG);
    for (int i = tid; i < avail; i += HEAD_BLK) s_nodes[i] = nodes[ebase + i];
    __syncthreads();

    const int g = g0 + tid;
    if (g >= G) return;
    const float* nd = &s_nodes[tid * NPG];

    float h1[4];
    #pragma unroll
    for (int k = 0; k < 4; ++k) h1[k] = s_b1[k];
    #pragma unroll
    for (int j = 0; j < NPG; ++j) {
        const float nj = nd[j];
        #pragma unroll
        for (int k = 0; k < 4; ++k) h1[k] = fmaf(nj, s_W1[j * 4 + k], h1[k]);
    }
    #pragma unroll
    for (int k = 0; k < 4; ++k) h1[k] = h1[k] >= 0.0f ? h1[k] : 0.01f * h1[k];

    float h2[4];
    #pragma unroll
    for (int k = 0; k < 4; ++k) {
        float a = s_b2[k];
        #pragma unroll
        for (int j = 0; j < 4; ++j) a = fmaf(h1[j], s_W2[j * 4 + k], a);
        h2[k] = a >= 0.0f ? a : 0.01f * a;
    }

    float h3[12];
    #pragma unroll
    for (int k = 0; k < 12; ++k) {
        float a = s_b3[k];
        #pragma unroll
        for (int j = 0; j < 4; ++j) a = fmaf(h2[j], s_W3[j * 12 + k], a);
        h3[k] = a >= 0.0f ? a : 0.01f * a;
    }

    float m = h3[0];
    #pragma unroll
    for (int k = 1; k < 12; ++k) m = fmaxf(m, h3[k]);
    float sum = 0.0f;
    #pragma unroll
    for (int k = 0; k < 12; ++k) { h3[k] = expf(h3[k] - m); sum += h3[k]; }
    const float inv = 1.0f / sum;

    float4* o = reinterpret_cast<float4*>(out + (size_t)g * 12);
    o[0] = make_float4(h3[0] * inv, h3[1] * inv, h3[2]  * inv, h3[3]  * inv);
    o[1] = make_float4(h3[4] * inv, h3[5] * inv, h3[6]  * inv, h3[7]  * inv);
    o[2] = make_float4(h3[8] * inv, h3[9] * inv, h3[10] * inv, h3[11] * inv);
}

extern "C" void kernel_launch(void* const* d_in, const int* in_sizes, int n_in,
                              void* d_out, int out_size, void* d_ws, size_t ws_size,
                              hipStream_t stream)
{
    const float* x      = (const float*)d_in[0];
    const int*   eidx   = (const int*)  d_in[1];
    const float* ea     = (const float*)d_in[2];
    const float* w_edge = (const float*)d_in[3];
    const float* b_edge = (const float*)d_in[4];
    const float* w_root = (const float*)d_in[5];
    const float* b_conv = (const float*)d_in[6];
    const float* W1 = (const float*)d_in[7];
    const float* b1 = (const float*)d_in[8];
    const float* W2 = (const float*)d_in[9];
    const float* b2 = (const float*)d_in[10];
    const float* W3 = (const float*)d_in[11];
    const float* b3 = (const float*)d_in[12];
    float* out = (float*)d_out;

    const int N = in_sizes[0];
    const int E = in_sizes[2];
    const int G = N / NPG;
    const int* src = eidx;
    const int* dst = eidx + E;
    const int nquads = E / 4;
    const int B = (N + SLICE - 1) >> SHIFT;     // 304 for this problem

    // workspace layout
    char* ws = (char*)d_ws;
    size_t off_pairs = 0;
    size_t sz_pairs  = (size_t)E * 8;
    size_t off_hist  = off_pairs + sz_pairs;
    size_t sz_hist   = (size_t)B * NB * 4;
    size_t off_tot   = off_hist + sz_hist;
    size_t off_base  = off_tot + (size_t)B * 4;
    size_t off_nodes = off_base + (size_t)B * 4;
    size_t need      = off_nodes + (size_t)N * 4;

    if (B <= BMAX && (E % 4) == 0 && need <= ws_size) {
        uint2* pairs  = (uint2*)(ws + off_pairs);
        int*   histM  = (int*)  (ws + off_hist);
        int*   totals = (int*)  (ws + off_tot);
        int*   bbase  = (int*)  (ws + off_base);
        float* nodes  = (float*)(ws + off_nodes);

        const int qpb = (nquads + NB - 1) / NB;
        k_hist <<<NB, ETHR, 0, stream>>>(dst, nquads, qpb, B, histM);
        k_scan1<<<B, 256, 0, stream>>>(histM, totals);
        k_scan2<<<1, 64, 0, stream>>>(totals, bbase, B);
        k_binA <<<NB, ETHR, 0, stream>>>(x, src, dst, ea, w_edge, b_edge,
                                         histM, bbase, pairs, nquads, qpb, B);
        k_binB <<<B, 1024, 0, stream>>>(pairs, bbase, totals, x, w_root, b_conv,
                                        nodes, N);
        const int hblocks = (G + HEAD_BLK - 1) / HEAD_BLK;
        head_kernel<<<hblocks, HEAD_BLK, 0, stream>>>(nodes, W1, b1, W2, b2,
                                                      W3, b3, out, G);
    } else {
        // fallback: global-atomic scatter (needs only 2N floats of ws)
        float* agg   = (float*)d_ws;
        float* nodes = agg + N;
        hipMemsetAsync(agg, 0, (size_t)N * sizeof(float), stream);
        edge_kernel_atomic<<<2048, 256, 0, stream>>>(x, src, dst, ea, w_edge,
                                                     b_edge, agg, nquads);
        finalize_nodes<<<2048, 256, 0, stream>>>(x, agg, w_root, b_conv, nodes, N);
        const int hblocks = (G + HEAD_BLK - 1) / HEAD_BLK;
        head_kernel<<<hblocks, HEAD_BLK, 0, stream>>>(nodes, W1, b1, W2, b2,
                                                      W3, b3, out, G);
    }
}

// Round 5
// 1686.027 us; speedup vs baseline: 1.4449x; 1.0017x over previous
//
#include <hip/hip_runtime.h>

#define NPG 38
#define HEAD_BLK 256
#define SHIFT 14
#define SLICE (1 << SHIFT)        // 16384 nodes per dst-bucket (64KB LDS in k_binB)
#define BMAX 320                  // max buckets supported (LDS cursor arrays)
#define NB 2048                   // blocks for hist / binA (chunked edge ranges)
#define ETHR 512                  // threads for hist / binA

// Clang native vectors for nontemporal vector loads
typedef int    v4i __attribute__((ext_vector_type(4)));
typedef float  v4f __attribute__((ext_vector_type(4)));
typedef unsigned int v2u __attribute__((ext_vector_type(2)));

// ---------------------------------------------------------------------------
// K1: per-block-chunk histogram of dst buckets (nt streaming reads)
// ---------------------------------------------------------------------------
__global__ __launch_bounds__(ETHR) void k_hist(
    const int* __restrict__ dst, int nquads, int qpb, int B,
    int* __restrict__ histM)                     // [B][NB]
{
    __shared__ int h[BMAX];
    for (int i = threadIdx.x; i < B; i += ETHR) h[i] = 0;
    __syncthreads();
    const int blk = blockIdx.x;
    const int q0 = blk * qpb;
    const int q1 = min(q0 + qpb, nquads);
    const v4i* d4 = (const v4i*)dst;
    for (int q = q0 + threadIdx.x; q < q1; q += ETHR) {
        v4i d = __builtin_nontemporal_load(d4 + q);
        atomicAdd(&h[d.x >> SHIFT], 1);
        atomicAdd(&h[d.y >> SHIFT], 1);
        atomicAdd(&h[d.z >> SHIFT], 1);
        atomicAdd(&h[d.w >> SHIFT], 1);
    }
    __syncthreads();
    for (int i = threadIdx.x; i < B; i += ETHR) histM[i * NB + blk] = h[i];
}

// ---------------------------------------------------------------------------
// K2: per-bucket exclusive scan across NB blocks (in place) + totals
// ---------------------------------------------------------------------------
__global__ __launch_bounds__(256) void k_scan1(
    int* __restrict__ histM, int* __restrict__ totals)
{
    __shared__ int v[NB];
    __shared__ int part[256];
    const int b = blockIdx.x;
    const int t = threadIdx.x;
    for (int i = t; i < NB; i += 256) v[i] = histM[b * NB + i];
    __syncthreads();
    int base = t * (NB / 256);
    int run = 0;
    #pragma unroll
    for (int i = 0; i < NB / 256; ++i) { int x = v[base + i]; v[base + i] = run; run += x; }
    part[t] = run;
    __syncthreads();
    if (t == 0) {
        int r = 0;
        for (int i = 0; i < 256; ++i) { int x = part[i]; part[i] = r; r += x; }
        totals[b] = r;
    }
    __syncthreads();
    const int p = part[t];
    #pragma unroll
    for (int i = 0; i < NB / 256; ++i) v[base + i] += p;
    __syncthreads();
    for (int i = t; i < NB; i += 256) histM[b * NB + i] = v[i];
}

// ---------------------------------------------------------------------------
// K3: exclusive scan of bucket totals -> bucket bases (B small)
// ---------------------------------------------------------------------------
__global__ void k_scan2(const int* __restrict__ totals, int* __restrict__ bbase, int B)
{
    if (threadIdx.x == 0 && blockIdx.x == 0) {
        int run = 0;
        for (int b = 0; b < B; ++b) { bbase[b] = run; run += totals[b]; }
    }
}

// ---------------------------------------------------------------------------
// K4: stream edges (nt), gather x[src] (cached), append (dst_local,msg) pairs.
// Streaming uses nt so it does not evict x-gather lines / partial write lines.
// ---------------------------------------------------------------------------
__global__ __launch_bounds__(ETHR) void k_binA(
    const float* __restrict__ x,
    const int* __restrict__ src, const int* __restrict__ dst,
    const float* __restrict__ ea,
    const float* __restrict__ w_edge, const float* __restrict__ b_edge,
    const int* __restrict__ histM, const int* __restrict__ bbase,
    uint2* __restrict__ pairs,
    int nquads, int qpb, int B)
{
    __shared__ int cur[BMAX];
    const int blk = blockIdx.x;
    for (int i = threadIdx.x; i < B; i += ETHR)
        cur[i] = bbase[i] + histM[i * NB + blk];
    __syncthreads();
    const float we = w_edge[0], be = b_edge[0];
    const int q0 = blk * qpb;
    const int q1 = min(q0 + qpb, nquads);
    const v4i* s4 = (const v4i*)src;
    const v4i* d4 = (const v4i*)dst;
    const v4f* e4 = (const v4f*)ea;
    for (int q = q0 + threadIdx.x; q < q1; q += ETHR) {
        v4i s = __builtin_nontemporal_load(s4 + q);
        v4i d = __builtin_nontemporal_load(d4 + q);
        v4f e = __builtin_nontemporal_load(e4 + q);
        float m0 = x[s.x] * fmaf(e.x, we, be);
        float m1 = x[s.y] * fmaf(e.y, we, be);
        float m2 = x[s.z] * fmaf(e.z, we, be);
        float m3 = x[s.w] * fmaf(e.w, we, be);
        int p0 = atomicAdd(&cur[d.x >> SHIFT], 1);
        pairs[p0] = make_uint2((unsigned)(d.x & (SLICE - 1)), __float_as_uint(m0));
        int p1 = atomicAdd(&cur[d.y >> SHIFT], 1);
        pairs[p1] = make_uint2((unsigned)(d.y & (SLICE - 1)), __float_as_uint(m1));
        int p2 = atomicAdd(&cur[d.z >> SHIFT], 1);
        pairs[p2] = make_uint2((unsigned)(d.z & (SLICE - 1)), __float_as_uint(m2));
        int p3 = atomicAdd(&cur[d.w >> SHIFT], 1);
        pairs[p3] = make_uint2((unsigned)(d.w & (SLICE - 1)), __float_as_uint(m3));
    }
}

// ---------------------------------------------------------------------------
// K5: per-bucket LDS accumulation of pairs (nt read) + root transform -> nodes
// ---------------------------------------------------------------------------
__global__ __launch_bounds__(1024) void k_binB(
    const uint2* __restrict__ pairs,
    const int* __restrict__ bbase, const int* __restrict__ totals,
    const float* __restrict__ x,
    const float* __restrict__ w_root, const float* __restrict__ b_conv,
    float* __restrict__ nodes, int N)
{
    __shared__ float slice[SLICE];               // 65536 B
    const int b = blockIdx.x;
    for (int i = threadIdx.x; i < SLICE; i += 1024) slice[i] = 0.0f;
    __syncthreads();
    const int p0 = bbase[b];
    const int p1 = p0 + totals[b];
    const v2u* pr = (const v2u*)pairs;
    for (int i = p0 + threadIdx.x; i < p1; i += 1024) {
        v2u p = __builtin_nontemporal_load(pr + i);
        atomicAdd(&slice[p.x], __uint_as_float(p.y));
    }
    __syncthreads();
    const float wr = w_root[0], bc = b_conv[0];
    const int gbase = b << SHIFT;
    for (int i = threadIdx.x; i < SLICE; i += 1024) {
        int gi = gbase + i;
        if (gi < N) nodes[gi] = slice[i] + fmaf(__builtin_nontemporal_load(x + gi), wr, bc);
    }
}

// ---------------------------------------------------------------------------
// Fallback edge kernel (global atomics) when workspace is too small
// ---------------------------------------------------------------------------
__global__ __launch_bounds__(256) void edge_kernel_atomic(
    const float* __restrict__ x,
    const int*   __restrict__ src, const int* __restrict__ dst,
    const float* __restrict__ ea,
    const float* __restrict__ w_edge, const float* __restrict__ b_edge,
    float* __restrict__ agg, int nquads)
{
    const float we = w_edge[0], be = b_edge[0];
    int tid = blockIdx.x * blockDim.x + threadIdx.x;
    int stride = gridDim.x * blockDim.x;
    const int4*   s4 = (const int4*)src;
    const int4*   d4 = (const int4*)dst;
    const float4* e4 = (const float4*)ea;
    for (int q = tid; q < nquads; q += stride) {
        int4 s = s4[q]; int4 d = d4[q]; float4 e = e4[q];
        atomicAdd(&agg[d.x], x[s.x] * fmaf(e.x, we, be));
        atomicAdd(&agg[d.y], x[s.y] * fmaf(e.y, we, be));
        atomicAdd(&agg[d.z], x[s.z] * fmaf(e.z, we, be));
        atomicAdd(&agg[d.w], x[s.w] * fmaf(e.w, we, be));
    }
}

__global__ __launch_bounds__(256) void finalize_nodes(
    const float* __restrict__ x, const float* __restrict__ agg,
    const float* __restrict__ w_root, const float* __restrict__ b_conv,
    float* __restrict__ nodes, int N)
{
    const float wr = w_root[0], bc = b_conv[0];
    int i = blockIdx.x * blockDim.x + threadIdx.x;
    int stride = gridDim.x * blockDim.x;
    for (; i < N; i += stride) nodes[i] = agg[i] + fmaf(x[i], wr, bc);
}

// ---------------------------------------------------------------------------
// K6: head MLP over per-graph node vectors + softmax
// ---------------------------------------------------------------------------
__global__ __launch_bounds__(HEAD_BLK) void head_kernel(
    const float* __restrict__ nodes,
    const float* __restrict__ W1, const float* __restrict__ b1,
    const float* __restrict__ W2, const float* __restrict__ b2,
    const float* __restrict__ W3, const float* __restrict__ b3,
    float* __restrict__ out, int G)
{
    __shared__ float s_nodes[HEAD_BLK * NPG];   // 38912 B
    __shared__ float s_W1[NPG * 4];
    __shared__ float s_W2[4 * 4];
    __shared__ float s_W3[4 * 12];
    __shared__ float s_b1[4];
    __shared__ float s_b2[4];
    __shared__ float s_b3[12];

    const int tid = threadIdx.x;
    if (tid < NPG * 4) s_W1[tid] = W1[tid];
    if (tid >= 160 && tid < 176) s_W2[tid - 160] = W2[tid - 160];
    if (tid >= 176 && tid < 224) s_W3[tid - 176] = W3[tid - 176];
    if (tid >= 224 && tid < 228) s_b1[tid - 224] = b1[tid - 224];
    if (tid >= 228 && tid < 232) s_b2[tid - 228] = b2[tid - 228];
    if (tid >= 232 && tid < 244) s_b3[tid - 232] = b3[tid - 232];

    const int g0 = blockIdx.x * HEAD_BLK;
    const size_t ebase = (size_t)g0 * NPG;
    const int nelem = HEAD_BLK * NPG;
    const int avail = min(nelem, (G - g0) * NPG);
    for (int i = tid; i < avail; i += HEAD_BLK) s_nodes[i] = nodes[ebase + i];
    __syncthreads();

    const int g = g0 + tid;
    if (g >= G) return;
    const float* nd = &s_nodes[tid * NPG];

    float h1[4];
    #pragma unroll
    for (int k = 0; k < 4; ++k) h1[k] = s_b1[k];
    #pragma unroll
    for (int j = 0; j < NPG; ++j) {
        const float nj = nd[j];
        #pragma unroll
        for (int k = 0; k < 4; ++k) h1[k] = fmaf(nj, s_W1[j * 4 + k], h1[k]);
    }
    #pragma unroll
    for (int k = 0; k < 4; ++k) h1[k] = h1[k] >= 0.0f ? h1[k] : 0.01f * h1[k];

    float h2[4];
    #pragma unroll
    for (int k = 0; k < 4; ++k) {
        float a = s_b2[k];
        #pragma unroll
        for (int j = 0; j < 4; ++j) a = fmaf(h1[j], s_W2[j * 4 + k], a);
        h2[k] = a >= 0.0f ? a : 0.01f * a;
    }

    float h3[12];
    #pragma unroll
    for (int k = 0; k < 12; ++k) {
        float a = s_b3[k];
        #pragma unroll
        for (int j = 0; j < 4; ++j) a = fmaf(h2[j], s_W3[j * 12 + k], a);
        h3[k] = a >= 0.0f ? a : 0.01f * a;
    }

    float m = h3[0];
    #pragma unroll
    for (int k = 1; k < 12; ++k) m = fmaxf(m, h3[k]);
    float sum = 0.0f;
    #pragma unroll
    for (int k = 0; k < 12; ++k) { h3[k] = expf(h3[k] - m); sum += h3[k]; }
    const float inv = 1.0f / sum;

    float4* o = reinterpret_cast<float4*>(out + (size_t)g * 12);
    o[0] = make_float4(h3[0] * inv, h3[1] * inv, h3[2]  * inv, h3[3]  * inv);
    o[1] = make_float4(h3[4] * inv, h3[5] * inv, h3[6]  * inv, h3[7]  * inv);
    o[2] = make_float4(h3[8] * inv, h3[9] * inv, h3[10] * inv, h3[11] * inv);
}

extern "C" void kernel_launch(void* const* d_in, const int* in_sizes, int n_in,
                              void* d_out, int out_size, void* d_ws, size_t ws_size,
                              hipStream_t stream)
{
    const float* x      = (const float*)d_in[0];
    const int*   eidx   = (const int*)  d_in[1];
    const float* ea     = (const float*)d_in[2];
    const float* w_edge = (const float*)d_in[3];
    const float* b_edge = (const float*)d_in[4];
    const float* w_root = (const float*)d_in[5];
    const float* b_conv = (const float*)d_in[6];
    const float* W1 = (const float*)d_in[7];
    const float* b1 = (const float*)d_in[8];
    const float* W2 = (const float*)d_in[9];
    const float* b2 = (const float*)d_in[10];
    const float* W3 = (const float*)d_in[11];
    const float* b3 = (const float*)d_in[12];
    float* out = (float*)d_out;

    const int N = in_sizes[0];
    const int E = in_sizes[2];
    const int G = N / NPG;
    const int* src = eidx;
    const int* dst = eidx + E;
    const int nquads = E / 4;
    const int B = (N + SLICE - 1) >> SHIFT;     // 304 for this problem

    // workspace layout
    char* ws = (char*)d_ws;
    size_t off_pairs = 0;
    size_t sz_pairs  = (size_t)E * 8;
    size_t off_hist  = off_pairs + sz_pairs;
    size_t sz_hist   = (size_t)B * NB * 4;
    size_t off_tot   = off_hist + sz_hist;
    size_t off_base  = off_tot + (size_t)B * 4;
    size_t off_nodes = off_base + (size_t)B * 4;
    size_t need      = off_nodes + (size_t)N * 4;

    if (B <= BMAX && (E % 4) == 0 && need <= ws_size) {
        uint2* pairs  = (uint2*)(ws + off_pairs);
        int*   histM  = (int*)  (ws + off_hist);
        int*   totals = (int*)  (ws + off_tot);
        int*   bbase  = (int*)  (ws + off_base);
        float* nodes  = (float*)(ws + off_nodes);

        const int qpb = (nquads + NB - 1) / NB;
        k_hist <<<NB, ETHR, 0, stream>>>(dst, nquads, qpb, B, histM);
        k_scan1<<<B, 256, 0, stream>>>(histM, totals);
        k_scan2<<<1, 64, 0, stream>>>(totals, bbase, B);
        k_binA <<<NB, ETHR, 0, stream>>>(x, src, dst, ea, w_edge, b_edge,
                                         histM, bbase, pairs, nquads, qpb, B);
        k_binB <<<B, 1024, 0, stream>>>(pairs, bbase, totals, x, w_root, b_conv,
                                        nodes, N);
        const int hblocks = (G + HEAD_BLK - 1) / HEAD_BLK;
        head_kernel<<<hblocks, HEAD_BLK, 0, stream>>>(nodes, W1, b1, W2, b2,
                                                      W3, b3, out, G);
    } else {
        // fallback: global-atomic scatter (needs only 2N floats of ws)
        float* agg   = (float*)d_ws;
        float* nodes = agg + N;
        hipMemsetAsync(agg, 0, (size_t)N * sizeof(float), stream);
        edge_kernel_atomic<<<2048, 256, 0, stream>>>(x, src, dst, ea, w_edge,
                                                     b_edge, agg, nquads);
        finalize_nodes<<<2048, 256, 0, stream>>>(x, agg, w_root, b_conv, nodes, N);
        const int hblocks = (G + HEAD_BLK - 1) / HEAD_BLK;
        head_kernel<<<hblocks, HEAD_BLK, 0, stream>>>(nodes, W1, b1, W2, b2,
                                                      W3, b3, out, G);
    }
}

// Round 6
// 1647.398 us; speedup vs baseline: 1.4787x; 1.0234x over previous
//
#include <hip/hip_runtime.h>

#define NPG 38
#define HEAD_BLK 256
#define SHIFT 14
#define SLICE (1 << SHIFT)        // 16384 nodes per dst-bucket (64KB LDS in k_binB)
#define BMAX 320                  // max buckets supported (LDS cursor arrays)
#define NB 1024                   // blocks for hist / binA (chunked edge ranges)
#define ETHR 512                  // threads for hist / binA

// Clang native vectors for nontemporal vector loads
typedef int    v4i __attribute__((ext_vector_type(4)));
typedef float  v4f __attribute__((ext_vector_type(4)));

// round-to-nearest-even f32 -> bf16 bits
static inline __device__ unsigned f2bf(float f) {
    unsigned u = __float_as_uint(f);
    return (u + 0x7FFFu + ((u >> 16) & 1u)) >> 16;
}

// ---------------------------------------------------------------------------
// K1: per-block-chunk histogram of dst buckets
// ---------------------------------------------------------------------------
__global__ __launch_bounds__(ETHR) void k_hist(
    const int* __restrict__ dst, int nquads, int qpb, int B,
    int* __restrict__ histM)                     // [B][NB]
{
    __shared__ int h[BMAX];
    for (int i = threadIdx.x; i < B; i += ETHR) h[i] = 0;
    __syncthreads();
    const int blk = blockIdx.x;
    const int q0 = blk * qpb;
    const int q1 = min(q0 + qpb, nquads);
    const v4i* d4 = (const v4i*)dst;
    for (int q = q0 + threadIdx.x; q < q1; q += ETHR) {
        v4i d = __builtin_nontemporal_load(d4 + q);
        atomicAdd(&h[d.x >> SHIFT], 1);
        atomicAdd(&h[d.y >> SHIFT], 1);
        atomicAdd(&h[d.z >> SHIFT], 1);
        atomicAdd(&h[d.w >> SHIFT], 1);
    }
    __syncthreads();
    for (int i = threadIdx.x; i < B; i += ETHR) histM[i * NB + blk] = h[i];
}

// ---------------------------------------------------------------------------
// K2: per-bucket exclusive scan across NB blocks (in place) + totals
// ---------------------------------------------------------------------------
__global__ __launch_bounds__(256) void k_scan1(
    int* __restrict__ histM, int* __restrict__ totals)
{
    __shared__ int v[NB];
    __shared__ int part[256];
    const int b = blockIdx.x;
    const int t = threadIdx.x;
    for (int i = t; i < NB; i += 256) v[i] = histM[b * NB + i];
    __syncthreads();
    int base = t * (NB / 256);
    int run = 0;
    #pragma unroll
    for (int i = 0; i < NB / 256; ++i) { int x = v[base + i]; v[base + i] = run; run += x; }
    part[t] = run;
    __syncthreads();
    if (t == 0) {
        int r = 0;
        for (int i = 0; i < 256; ++i) { int x = part[i]; part[i] = r; r += x; }
        totals[b] = r;
    }
    __syncthreads();
    const int p = part[t];
    #pragma unroll
    for (int i = 0; i < NB / 256; ++i) v[base + i] += p;
    __syncthreads();
    for (int i = t; i < NB; i += 256) histM[b * NB + i] = v[i];
}

// ---------------------------------------------------------------------------
// K3: exclusive scan of bucket totals -> bucket bases (B small)
// ---------------------------------------------------------------------------
__global__ void k_scan2(const int* __restrict__ totals, int* __restrict__ bbase, int B)
{
    if (threadIdx.x == 0 && blockIdx.x == 0) {
        int run = 0;
        for (int b = 0; b < B; ++b) { bbase[b] = run; run += totals[b]; }
    }
}

// ---------------------------------------------------------------------------
// K4: stream edges, gather x[src], compute msg, append packed 4B pair
// (dst_local<<16 | bf16(msg)) at the exact precomputed slot. No global atomics.
// ---------------------------------------------------------------------------
__global__ __launch_bounds__(ETHR) void k_binA(
    const float* __restrict__ x,
    const int* __restrict__ src, const int* __restrict__ dst,
    const float* __restrict__ ea,
    const float* __restrict__ w_edge, const float* __restrict__ b_edge,
    const int* __restrict__ histM, const int* __restrict__ bbase,
    unsigned* __restrict__ pairs,
    int nquads, int qpb, int B)
{
    __shared__ int cur[BMAX];
    const int blk = blockIdx.x;
    for (int i = threadIdx.x; i < B; i += ETHR)
        cur[i] = bbase[i] + histM[i * NB + blk];
    __syncthreads();
    const float we = w_edge[0], be = b_edge[0];
    const int q0 = blk * qpb;
    const int q1 = min(q0 + qpb, nquads);
    const v4i* s4 = (const v4i*)src;
    const v4i* d4 = (const v4i*)dst;
    const v4f* e4 = (const v4f*)ea;
    for (int q = q0 + threadIdx.x; q < q1; q += ETHR) {
        v4i s = __builtin_nontemporal_load(s4 + q);
        v4i d = __builtin_nontemporal_load(d4 + q);
        v4f e = __builtin_nontemporal_load(e4 + q);
        float m0 = x[s.x] * fmaf(e.x, we, be);
        float m1 = x[s.y] * fmaf(e.y, we, be);
        float m2 = x[s.z] * fmaf(e.z, we, be);
        float m3 = x[s.w] * fmaf(e.w, we, be);
        int p0 = atomicAdd(&cur[d.x >> SHIFT], 1);
        pairs[p0] = ((unsigned)(d.x & (SLICE - 1)) << 16) | f2bf(m0);
        int p1 = atomicAdd(&cur[d.y >> SHIFT], 1);
        pairs[p1] = ((unsigned)(d.y & (SLICE - 1)) << 16) | f2bf(m1);
        int p2 = atomicAdd(&cur[d.z >> SHIFT], 1);
        pairs[p2] = ((unsigned)(d.z & (SLICE - 1)) << 16) | f2bf(m2);
        int p3 = atomicAdd(&cur[d.w >> SHIFT], 1);
        pairs[p3] = ((unsigned)(d.w & (SLICE - 1)) << 16) | f2bf(m3);
    }
}

// ---------------------------------------------------------------------------
// K5: per-bucket LDS accumulation of packed pairs + root transform -> nodes
// ---------------------------------------------------------------------------
__global__ __launch_bounds__(1024) void k_binB(
    const unsigned* __restrict__ pairs,
    const int* __restrict__ bbase, const int* __restrict__ totals,
    const float* __restrict__ x,
    const float* __restrict__ w_root, const float* __restrict__ b_conv,
    float* __restrict__ nodes, int N)
{
    __shared__ float slice[SLICE];               // 65536 B
    const int b = blockIdx.x;
    for (int i = threadIdx.x; i < SLICE; i += 1024) slice[i] = 0.0f;
    __syncthreads();
    const int p0 = bbase[b];
    const int p1 = p0 + totals[b];
    for (int i = p0 + threadIdx.x; i < p1; i += 1024) {
        unsigned p = __builtin_nontemporal_load(pairs + i);
        atomicAdd(&slice[p >> 16], __uint_as_float(p << 16));
    }
    __syncthreads();
    const float wr = w_root[0], bc = b_conv[0];
    const int gbase = b << SHIFT;
    for (int i = threadIdx.x; i < SLICE; i += 1024) {
        int gi = gbase + i;
        if (gi < N) nodes[gi] = slice[i] + fmaf(__builtin_nontemporal_load(x + gi), wr, bc);
    }
}

// ---------------------------------------------------------------------------
// Fallback edge kernel (global atomics) when workspace is too small
// ---------------------------------------------------------------------------
__global__ __launch_bounds__(256) void edge_kernel_atomic(
    const float* __restrict__ x,
    const int*   __restrict__ src, const int* __restrict__ dst,
    const float* __restrict__ ea,
    const float* __restrict__ w_edge, const float* __restrict__ b_edge,
    float* __restrict__ agg, int nquads)
{
    const float we = w_edge[0], be = b_edge[0];
    int tid = blockIdx.x * blockDim.x + threadIdx.x;
    int stride = gridDim.x * blockDim.x;
    const int4*   s4 = (const int4*)src;
    const int4*   d4 = (const int4*)dst;
    const float4* e4 = (const float4*)ea;
    for (int q = tid; q < nquads; q += stride) {
        int4 s = s4[q]; int4 d = d4[q]; float4 e = e4[q];
        atomicAdd(&agg[d.x], x[s.x] * fmaf(e.x, we, be));
        atomicAdd(&agg[d.y], x[s.y] * fmaf(e.y, we, be));
        atomicAdd(&agg[d.z], x[s.z] * fmaf(e.z, we, be));
        atomicAdd(&agg[d.w], x[s.w] * fmaf(e.w, we, be));
    }
}

__global__ __launch_bounds__(256) void finalize_nodes(
    const float* __restrict__ x, const float* __restrict__ agg,
    const float* __restrict__ w_root, const float* __restrict__ b_conv,
    float* __restrict__ nodes, int N)
{
    const float wr = w_root[0], bc = b_conv[0];
    int i = blockIdx.x * blockDim.x + threadIdx.x;
    int stride = gridDim.x * blockDim.x;
    for (; i < N; i += stride) nodes[i] = agg[i] + fmaf(x[i], wr, bc);
}

// ---------------------------------------------------------------------------
// K6: head MLP over per-graph node vectors + softmax
// ---------------------------------------------------------------------------
__global__ __launch_bounds__(HEAD_BLK) void head_kernel(
    const float* __restrict__ nodes,
    const float* __restrict__ W1, const float* __restrict__ b1,
    const float* __restrict__ W2, const float* __restrict__ b2,
    const float* __restrict__ W3, const float* __restrict__ b3,
    float* __restrict__ out, int G)
{
    __shared__ float s_nodes[HEAD_BLK * NPG];   // 38912 B
    __shared__ float s_W1[NPG * 4];
    __shared__ float s_W2[4 * 4];
    __shared__ float s_W3[4 * 12];
    __shared__ float s_b1[4];
    __shared__ float s_b2[4];
    __shared__ float s_b3[12];

    const int tid = threadIdx.x;
    if (tid < NPG * 4) s_W1[tid] = W1[tid];
    if (tid >= 160 && tid < 176) s_W2[tid - 160] = W2[tid - 160];
    if (tid >= 176 && tid < 224) s_W3[tid - 176] = W3[tid - 176];
    if (tid >= 224 && tid < 228) s_b1[tid - 224] = b1[tid - 224];
    if (tid >= 228 && tid < 232) s_b2[tid - 228] = b2[tid - 228];
    if (tid >= 232 && tid < 244) s_b3[tid - 232] = b3[tid - 232];

    const int g0 = blockIdx.x * HEAD_BLK;
    const size_t ebase = (size_t)g0 * NPG;
    const int nelem = HEAD_BLK * NPG;
    const int avail = min(nelem, (G - g0) * NPG);
    for (int i = tid; i < avail; i += HEAD_BLK) s_nodes[i] = nodes[ebase + i];
    __syncthreads();

    const int g = g0 + tid;
    if (g >= G) return;
    const float* nd = &s_nodes[tid * NPG];

    float h1[4];
    #pragma unroll
    for (int k = 0; k < 4; ++k) h1[k] = s_b1[k];
    #pragma unroll
    for (int j = 0; j < NPG; ++j) {
        const float nj = nd[j];
        #pragma unroll
        for (int k = 0; k < 4; ++k) h1[k] = fmaf(nj, s_W1[j * 4 + k], h1[k]);
    }
    #pragma unroll
    for (int k = 0; k < 4; ++k) h1[k] = h1[k] >= 0.0f ? h1[k] : 0.01f * h1[k];

    float h2[4];
    #pragma unroll
    for (int k = 0; k < 4; ++k) {
        float a = s_b2[k];
        #pragma unroll
        for (int j = 0; j < 4; ++j) a = fmaf(h1[j], s_W2[j * 4 + k], a);
        h2[k] = a >= 0.0f ? a : 0.01f * a;
    }

    float h3[12];
    #pragma unroll
    for (int k = 0; k < 12; ++k) {
        float a = s_b3[k];
        #pragma unroll
        for (int j = 0; j < 4; ++j) a = fmaf(h2[j], s_W3[j * 12 + k], a);
        h3[k] = a >= 0.0f ? a : 0.01f * a;
    }

    float m = h3[0];
    #pragma unroll
    for (int k = 1; k < 12; ++k) m = fmaxf(m, h3[k]);
    float sum = 0.0f;
    #pragma unroll
    for (int k = 0; k < 12; ++k) { h3[k] = expf(h3[k] - m); sum += h3[k]; }
    const float inv = 1.0f / sum;

    float4* o = reinterpret_cast<float4*>(out + (size_t)g * 12);
    o[0] = make_float4(h3[0] * inv, h3[1] * inv, h3[2]  * inv, h3[3]  * inv);
    o[1] = make_float4(h3[4] * inv, h3[5] * inv, h3[6]  * inv, h3[7]  * inv);
    o[2] = make_float4(h3[8] * inv, h3[9] * inv, h3[10] * inv, h3[11] * inv);
}

extern "C" void kernel_launch(void* const* d_in, const int* in_sizes, int n_in,
                              void* d_out, int out_size, void* d_ws, size_t ws_size,
                              hipStream_t stream)
{
    const float* x      = (const float*)d_in[0];
    const int*   eidx   = (const int*)  d_in[1];
    const float* ea     = (const float*)d_in[2];
    const float* w_edge = (const float*)d_in[3];
    const float* b_edge = (const float*)d_in[4];
    const float* w_root = (const float*)d_in[5];
    const float* b_conv = (const float*)d_in[6];
    const float* W1 = (const float*)d_in[7];
    const float* b1 = (const float*)d_in[8];
    const float* W2 = (const float*)d_in[9];
    const float* b2 = (const float*)d_in[10];
    const float* W3 = (const float*)d_in[11];
    const float* b3 = (const float*)d_in[12];
    float* out = (float*)d_out;

    const int N = in_sizes[0];
    const int E = in_sizes[2];
    const int G = N / NPG;
    const int* src = eidx;
    const int* dst = eidx + E;
    const int nquads = E / 4;
    const int B = (N + SLICE - 1) >> SHIFT;     // 304 for this problem

    // workspace layout
    char* ws = (char*)d_ws;
    size_t off_pairs = 0;
    size_t sz_pairs  = (size_t)E * 4;           // packed 4B pairs
    size_t off_hist  = off_pairs + sz_pairs;
    size_t sz_hist   = (size_t)B * NB * 4;
    size_t off_tot   = off_hist + sz_hist;
    size_t off_base  = off_tot + (size_t)B * 4;
    size_t off_nodes = off_base + (size_t)B * 4;
    size_t need      = off_nodes + (size_t)N * 4;

    if (B <= BMAX && (E % 4) == 0 && need <= ws_size) {
        unsigned* pairs  = (unsigned*)(ws + off_pairs);
        int*   histM  = (int*)  (ws + off_hist);
        int*   totals = (int*)  (ws + off_tot);
        int*   bbase  = (int*)  (ws + off_base);
        float* nodes  = (float*)(ws + off_nodes);

        const int qpb = (nquads + NB - 1) / NB;
        k_hist <<<NB, ETHR, 0, stream>>>(dst, nquads, qpb, B, histM);
        k_scan1<<<B, 256, 0, stream>>>(histM, totals);
        k_scan2<<<1, 64, 0, stream>>>(totals, bbase, B);
        k_binA <<<NB, ETHR, 0, stream>>>(x, src, dst, ea, w_edge, b_edge,
                                         histM, bbase, pairs, nquads, qpb, B);
        k_binB <<<B, 1024, 0, stream>>>(pairs, bbase, totals, x, w_root, b_conv,
                                        nodes, N);
        const int hblocks = (G + HEAD_BLK - 1) / HEAD_BLK;
        head_kernel<<<hblocks, HEAD_BLK, 0, stream>>>(nodes, W1, b1, W2, b2,
                                                      W3, b3, out, G);
    } else {
        // fallback: global-atomic scatter (needs only 2N floats of ws)
        float* agg   = (float*)d_ws;
        float* nodes = agg + N;
        hipMemsetAsync(agg, 0, (size_t)N * sizeof(float), stream);
        edge_kernel_atomic<<<2048, 256, 0, stream>>>(x, src, dst, ea, w_edge,
                                                     b_edge, agg, nquads);
        finalize_nodes<<<2048, 256, 0, stream>>>(x, agg, w_root, b_conv, nodes, N);
        const int hblocks = (G + HEAD_BLK - 1) / HEAD_BLK;
        head_kernel<<<hblocks, HEAD_BLK, 0, stream>>>(nodes, W1, b1, W2, b2,
                                                      W3, b3, out, G);
    }
}

// Round 7
// 1597.596 us; speedup vs baseline: 1.5248x; 1.0312x over previous
//
#include <hip/hip_runtime.h>

#define NPG 38
#define HEAD_BLK 256
#define SHIFT 14
#define SLICE (1 << SHIFT)        // 16384 nodes per dst-bucket (64KB LDS in k_binB)
#define BMAX 320                  // max buckets supported (LDS cursor arrays)
#define NB 1024                   // blocks for hist / binA (chunked edge ranges)
#define ETHR 512                  // threads for hist / binA

// Clang native vectors for nontemporal vector loads
typedef int    v4i __attribute__((ext_vector_type(4)));
typedef float  v4f __attribute__((ext_vector_type(4)));

// round-to-nearest-even f32 -> bf16 bits
static inline __device__ unsigned f2bf(float f) {
    unsigned u = __float_as_uint(f);
    return (u + 0x7FFFu + ((u >> 16) & 1u)) >> 16;
}

// ---------------------------------------------------------------------------
// K1: per-block-chunk histogram of dst buckets
// ---------------------------------------------------------------------------
__global__ __launch_bounds__(ETHR) void k_hist(
    const int* __restrict__ dst, int nquads, int qpb, int B,
    int* __restrict__ histM)                     // [B][NB]
{
    __shared__ int h[BMAX];
    for (int i = threadIdx.x; i < B; i += ETHR) h[i] = 0;
    __syncthreads();
    const int blk = blockIdx.x;
    const int q0 = blk * qpb;
    const int q1 = min(q0 + qpb, nquads);
    const v4i* d4 = (const v4i*)dst;
    for (int q = q0 + threadIdx.x; q < q1; q += ETHR) {
        v4i d = __builtin_nontemporal_load(d4 + q);
        atomicAdd(&h[d.x >> SHIFT], 1);
        atomicAdd(&h[d.y >> SHIFT], 1);
        atomicAdd(&h[d.z >> SHIFT], 1);
        atomicAdd(&h[d.w >> SHIFT], 1);
    }
    __syncthreads();
    for (int i = threadIdx.x; i < B; i += ETHR) histM[i * NB + blk] = h[i];
}

// ---------------------------------------------------------------------------
// K2: per-bucket exclusive scan across NB blocks (in place) + totals
// ---------------------------------------------------------------------------
__global__ __launch_bounds__(256) void k_scan1(
    int* __restrict__ histM, int* __restrict__ totals)
{
    __shared__ int v[NB];
    __shared__ int part[256];
    const int b = blockIdx.x;
    const int t = threadIdx.x;
    for (int i = t; i < NB; i += 256) v[i] = histM[b * NB + i];
    __syncthreads();
    int base = t * (NB / 256);
    int run = 0;
    #pragma unroll
    for (int i = 0; i < NB / 256; ++i) { int x = v[base + i]; v[base + i] = run; run += x; }
    part[t] = run;
    __syncthreads();
    if (t == 0) {
        int r = 0;
        for (int i = 0; i < 256; ++i) { int x = part[i]; part[i] = r; r += x; }
        totals[b] = r;
    }
    __syncthreads();
    const int p = part[t];
    #pragma unroll
    for (int i = 0; i < NB / 256; ++i) v[base + i] += p;
    __syncthreads();
    for (int i = t; i < NB; i += 256) histM[b * NB + i] = v[i];
}

// ---------------------------------------------------------------------------
// K3: exclusive scan of bucket totals -> bucket bases (B small)
// ---------------------------------------------------------------------------
__global__ void k_scan2(const int* __restrict__ totals, int* __restrict__ bbase, int B)
{
    if (threadIdx.x == 0 && blockIdx.x == 0) {
        int run = 0;
        for (int b = 0; b < B; ++b) { bbase[b] = run; run += totals[b]; }
    }
}

// ---------------------------------------------------------------------------
// K4: stream edges, gather x[src], compute msg, append packed 4B pair
// (dst_local<<16 | bf16(msg)). Unrolled x2: all loads issued before any
// dependent use -> 8 gather lines in flight per thread (MLP for latency).
// ---------------------------------------------------------------------------
__global__ __launch_bounds__(ETHR) void k_binA(
    const float* __restrict__ x,
    const int* __restrict__ src, const int* __restrict__ dst,
    const float* __restrict__ ea,
    const float* __restrict__ w_edge, const float* __restrict__ b_edge,
    const int* __restrict__ histM, const int* __restrict__ bbase,
    unsigned* __restrict__ pairs,
    int nquads, int qpb, int B)
{
    __shared__ int cur[BMAX];
    const int blk = blockIdx.x;
    for (int i = threadIdx.x; i < B; i += ETHR)
        cur[i] = bbase[i] + histM[i * NB + blk];
    __syncthreads();
    const float we = w_edge[0], be = b_edge[0];
    const int q0 = blk * qpb;
    const int q1 = min(q0 + qpb, nquads);
    const v4i* s4 = (const v4i*)src;
    const v4i* d4 = (const v4i*)dst;
    const v4f* e4 = (const v4f*)ea;

    int q = q0 + threadIdx.x;
    for (; q + ETHR < q1; q += 2 * ETHR) {
        // --- phase 1: all independent stream loads ---
        v4i sA = __builtin_nontemporal_load(s4 + q);
        v4i sB = __builtin_nontemporal_load(s4 + q + ETHR);
        v4i dA = __builtin_nontemporal_load(d4 + q);
        v4i dB = __builtin_nontemporal_load(d4 + q + ETHR);
        v4f eA = __builtin_nontemporal_load(e4 + q);
        v4f eB = __builtin_nontemporal_load(e4 + q + ETHR);
        // --- phase 2: 8 independent gathers in flight ---
        float xa0 = x[sA.x], xa1 = x[sA.y], xa2 = x[sA.z], xa3 = x[sA.w];
        float xb0 = x[sB.x], xb1 = x[sB.y], xb2 = x[sB.z], xb3 = x[sB.w];
        // --- phase 3: compute + append ---
        float mA0 = xa0 * fmaf(eA.x, we, be);
        float mA1 = xa1 * fmaf(eA.y, we, be);
        float mA2 = xa2 * fmaf(eA.z, we, be);
        float mA3 = xa3 * fmaf(eA.w, we, be);
        float mB0 = xb0 * fmaf(eB.x, we, be);
        float mB1 = xb1 * fmaf(eB.y, we, be);
        float mB2 = xb2 * fmaf(eB.z, we, be);
        float mB3 = xb3 * fmaf(eB.w, we, be);
        int p;
        p = atomicAdd(&cur[dA.x >> SHIFT], 1);
        pairs[p] = ((unsigned)(dA.x & (SLICE - 1)) << 16) | f2bf(mA0);
        p = atomicAdd(&cur[dA.y >> SHIFT], 1);
        pairs[p] = ((unsigned)(dA.y & (SLICE - 1)) << 16) | f2bf(mA1);
        p = atomicAdd(&cur[dA.z >> SHIFT], 1);
        pairs[p] = ((unsigned)(dA.z & (SLICE - 1)) << 16) | f2bf(mA2);
        p = atomicAdd(&cur[dA.w >> SHIFT], 1);
        pairs[p] = ((unsigned)(dA.w & (SLICE - 1)) << 16) | f2bf(mA3);
        p = atomicAdd(&cur[dB.x >> SHIFT], 1);
        pairs[p] = ((unsigned)(dB.x & (SLICE - 1)) << 16) | f2bf(mB0);
        p = atomicAdd(&cur[dB.y >> SHIFT], 1);
        pairs[p] = ((unsigned)(dB.y & (SLICE - 1)) << 16) | f2bf(mB1);
        p = atomicAdd(&cur[dB.z >> SHIFT], 1);
        pairs[p] = ((unsigned)(dB.z & (SLICE - 1)) << 16) | f2bf(mB2);
        p = atomicAdd(&cur[dB.w >> SHIFT], 1);
        pairs[p] = ((unsigned)(dB.w & (SLICE - 1)) << 16) | f2bf(mB3);
    }
    if (q < q1) {
        v4i s = __builtin_nontemporal_load(s4 + q);
        v4i d = __builtin_nontemporal_load(d4 + q);
        v4f e = __builtin_nontemporal_load(e4 + q);
        float m0 = x[s.x] * fmaf(e.x, we, be);
        float m1 = x[s.y] * fmaf(e.y, we, be);
        float m2 = x[s.z] * fmaf(e.z, we, be);
        float m3 = x[s.w] * fmaf(e.w, we, be);
        int p;
        p = atomicAdd(&cur[d.x >> SHIFT], 1);
        pairs[p] = ((unsigned)(d.x & (SLICE - 1)) << 16) | f2bf(m0);
        p = atomicAdd(&cur[d.y >> SHIFT], 1);
        pairs[p] = ((unsigned)(d.y & (SLICE - 1)) << 16) | f2bf(m1);
        p = atomicAdd(&cur[d.z >> SHIFT], 1);
        pairs[p] = ((unsigned)(d.z & (SLICE - 1)) << 16) | f2bf(m2);
        p = atomicAdd(&cur[d.w >> SHIFT], 1);
        pairs[p] = ((unsigned)(d.w & (SLICE - 1)) << 16) | f2bf(m3);
    }
}

// ---------------------------------------------------------------------------
// K5: per-bucket LDS accumulation of packed pairs + root transform -> nodes
// ---------------------------------------------------------------------------
__global__ __launch_bounds__(1024) void k_binB(
    const unsigned* __restrict__ pairs,
    const int* __restrict__ bbase, const int* __restrict__ totals,
    const float* __restrict__ x,
    const float* __restrict__ w_root, const float* __restrict__ b_conv,
    float* __restrict__ nodes, int N)
{
    __shared__ float slice[SLICE];               // 65536 B
    const int b = blockIdx.x;
    for (int i = threadIdx.x; i < SLICE; i += 1024) slice[i] = 0.0f;
    __syncthreads();
    const int p0 = bbase[b];
    const int p1 = p0 + totals[b];
    for (int i = p0 + threadIdx.x; i < p1; i += 1024) {
        unsigned p = __builtin_nontemporal_load(pairs + i);
        atomicAdd(&slice[p >> 16], __uint_as_float(p << 16));
    }
    __syncthreads();
    const float wr = w_root[0], bc = b_conv[0];
    const int gbase = b << SHIFT;
    for (int i = threadIdx.x; i < SLICE; i += 1024) {
        int gi = gbase + i;
        if (gi < N) nodes[gi] = slice[i] + fmaf(__builtin_nontemporal_load(x + gi), wr, bc);
    }
}

// ---------------------------------------------------------------------------
// Fallback edge kernel (global atomics) when workspace is too small
// ---------------------------------------------------------------------------
__global__ __launch_bounds__(256) void edge_kernel_atomic(
    const float* __restrict__ x,
    const int*   __restrict__ src, const int* __restrict__ dst,
    const float* __restrict__ ea,
    const float* __restrict__ w_edge, const float* __restrict__ b_edge,
    float* __restrict__ agg, int nquads)
{
    const float we = w_edge[0], be = b_edge[0];
    int tid = blockIdx.x * blockDim.x + threadIdx.x;
    int stride = gridDim.x * blockDim.x;
    const int4*   s4 = (const int4*)src;
    const int4*   d4 = (const int4*)dst;
    const float4* e4 = (const float4*)ea;
    for (int q = tid; q < nquads; q += stride) {
        int4 s = s4[q]; int4 d = d4[q]; float4 e = e4[q];
        atomicAdd(&agg[d.x], x[s.x] * fmaf(e.x, we, be));
        atomicAdd(&agg[d.y], x[s.y] * fmaf(e.y, we, be));
        atomicAdd(&agg[d.z], x[s.z] * fmaf(e.z, we, be));
        atomicAdd(&agg[d.w], x[s.w] * fmaf(e.w, we, be));
    }
}

__global__ __launch_bounds__(256) void finalize_nodes(
    const float* __restrict__ x, const float* __restrict__ agg,
    const float* __restrict__ w_root, const float* __restrict__ b_conv,
    float* __restrict__ nodes, int N)
{
    const float wr = w_root[0], bc = b_conv[0];
    int i = blockIdx.x * blockDim.x + threadIdx.x;
    int stride = gridDim.x * blockDim.x;
    for (; i < N; i += stride) nodes[i] = agg[i] + fmaf(x[i], wr, bc);
}

// ---------------------------------------------------------------------------
// K6: head MLP over per-graph node vectors + softmax
// ---------------------------------------------------------------------------
__global__ __launch_bounds__(HEAD_BLK) void head_kernel(
    const float* __restrict__ nodes,
    const float* __restrict__ W1, const float* __restrict__ b1,
    const float* __restrict__ W2, const float* __restrict__ b2,
    const float* __restrict__ W3, const float* __restrict__ b3,
    float* __restrict__ out, int G)
{
    __shared__ float s_nodes[HEAD_BLK * NPG];   // 38912 B
    __shared__ float s_W1[NPG * 4];
    __shared__ float s_W2[4 * 4];
    __shared__ float s_W3[4 * 12];
    __shared__ float s_b1[4];
    __shared__ float s_b2[4];
    __shared__ float s_b3[12];

    const int tid = threadIdx.x;
    if (tid < NPG * 4) s_W1[tid] = W1[tid];
    if (tid >= 160 && tid < 176) s_W2[tid - 160] = W2[tid - 160];
    if (tid >= 176 && tid < 224) s_W3[tid - 176] = W3[tid - 176];
    if (tid >= 224 && tid < 228) s_b1[tid - 224] = b1[tid - 224];
    if (tid >= 228 && tid < 232) s_b2[tid - 228] = b2[tid - 228];
    if (tid >= 232 && tid < 244) s_b3[tid - 232] = b3[tid - 232];

    const int g0 = blockIdx.x * HEAD_BLK;
    const size_t ebase = (size_t)g0 * NPG;
    const int nelem = HEAD_BLK * NPG;
    const int avail = min(nelem, (G - g0) * NPG);
    for (int i = tid; i < avail; i += HEAD_BLK) s_nodes[i] = nodes[ebase + i];
    __syncthreads();

    const int g = g0 + tid;
    if (g >= G) return;
    const float* nd = &s_nodes[tid * NPG];

    float h1[4];
    #pragma unroll
    for (int k = 0; k < 4; ++k) h1[k] = s_b1[k];
    #pragma unroll
    for (int j = 0; j < NPG; ++j) {
        const float nj = nd[j];
        #pragma unroll
        for (int k = 0; k < 4; ++k) h1[k] = fmaf(nj, s_W1[j * 4 + k], h1[k]);
    }
    #pragma unroll
    for (int k = 0; k < 4; ++k) h1[k] = h1[k] >= 0.0f ? h1[k] : 0.01f * h1[k];

    float h2[4];
    #pragma unroll
    for (int k = 0; k < 4; ++k) {
        float a = s_b2[k];
        #pragma unroll
        for (int j = 0; j < 4; ++j) a = fmaf(h1[j], s_W2[j * 4 + k], a);
        h2[k] = a >= 0.0f ? a : 0.01f * a;
    }

    float h3[12];
    #pragma unroll
    for (int k = 0; k < 12; ++k) {
        float a = s_b3[k];
        #pragma unroll
        for (int j = 0; j < 4; ++j) a = fmaf(h2[j], s_W3[j * 12 + k], a);
        h3[k] = a >= 0.0f ? a : 0.01f * a;
    }

    float m = h3[0];
    #pragma unroll
    for (int k = 1; k < 12; ++k) m = fmaxf(m, h3[k]);
    float sum = 0.0f;
    #pragma unroll
    for (int k = 0; k < 12; ++k) { h3[k] = expf(h3[k] - m); sum += h3[k]; }
    const float inv = 1.0f / sum;

    float4* o = reinterpret_cast<float4*>(out + (size_t)g * 12);
    o[0] = make_float4(h3[0] * inv, h3[1] * inv, h3[2]  * inv, h3[3]  * inv);
    o[1] = make_float4(h3[4] * inv, h3[5] * inv, h3[6]  * inv, h3[7]  * inv);
    o[2] = make_float4(h3[8] * inv, h3[9] * inv, h3[10] * inv, h3[11] * inv);
}

extern "C" void kernel_launch(void* const* d_in, const int* in_sizes, int n_in,
                              void* d_out, int out_size, void* d_ws, size_t ws_size,
                              hipStream_t stream)
{
    const float* x      = (const float*)d_in[0];
    const int*   eidx   = (const int*)  d_in[1];
    const float* ea     = (const float*)d_in[2];
    const float* w_edge = (const float*)d_in[3];
    const float* b_edge = (const float*)d_in[4];
    const float* w_root = (const float*)d_in[5];
    const float* b_conv = (const float*)d_in[6];
    const float* W1 = (const float*)d_in[7];
    const float* b1 = (const float*)d_in[8];
    const float* W2 = (const float*)d_in[9];
    const float* b2 = (const float*)d_in[10];
    const float* W3 = (const float*)d_in[11];
    const float* b3 = (const float*)d_in[12];
    float* out = (float*)d_out;

    const int N = in_sizes[0];
    const int E = in_sizes[2];
    const int G = N / NPG;
    const int* src = eidx;
    const int* dst = eidx + E;
    const int nquads = E / 4;
    const int B = (N + SLICE - 1) >> SHIFT;     // 304 for this problem

    // workspace layout
    char* ws = (char*)d_ws;
    size_t off_pairs = 0;
    size_t sz_pairs  = (size_t)E * 4;           // packed 4B pairs
    size_t off_hist  = off_pairs + sz_pairs;
    size_t sz_hist   = (size_t)B * NB * 4;
    size_t off_tot   = off_hist + sz_hist;
    size_t off_base  = off_tot + (size_t)B * 4;
    size_t off_nodes = off_base + (size_t)B * 4;
    size_t need      = off_nodes + (size_t)N * 4;

    if (B <= BMAX && (E % 4) == 0 && need <= ws_size) {
        unsigned* pairs  = (unsigned*)(ws + off_pairs);
        int*   histM  = (int*)  (ws + off_hist);
        int*   totals = (int*)  (ws + off_tot);
        int*   bbase  = (int*)  (ws + off_base);
        float* nodes  = (float*)(ws + off_nodes);

        const int qpb = (nquads + NB - 1) / NB;
        k_hist <<<NB, ETHR, 0, stream>>>(dst, nquads, qpb, B, histM);
        k_scan1<<<B, 256, 0, stream>>>(histM, totals);
        k_scan2<<<1, 64, 0, stream>>>(totals, bbase, B);
        k_binA <<<NB, ETHR, 0, stream>>>(x, src, dst, ea, w_edge, b_edge,
                                         histM, bbase, pairs, nquads, qpb, B);
        k_binB <<<B, 1024, 0, stream>>>(pairs, bbase, totals, x, w_root, b_conv,
                                        nodes, N);
        const int hblocks = (G + HEAD_BLK - 1) / HEAD_BLK;
        head_kernel<<<hblocks, HEAD_BLK, 0, stream>>>(nodes, W1, b1, W2, b2,
                                                      W3, b3, out, G);
    } else {
        // fallback: global-atomic scatter (needs only 2N floats of ws)
        float* agg   = (float*)d_ws;
        float* nodes = agg + N;
        hipMemsetAsync(agg, 0, (size_t)N * sizeof(float), stream);
        edge_kernel_atomic<<<2048, 256, 0, stream>>>(x, src, dst, ea, w_edge,
                                                     b_edge, agg, nquads);
        finalize_nodes<<<2048, 256, 0, stream>>>(x, agg, w_root, b_conv, nodes, N);
        const int hblocks = (G + HEAD_BLK - 1) / HEAD_BLK;
        head_kernel<<<hblocks, HEAD_BLK, 0, stream>>>(nodes, W1, b1, W2, b2,
                                                      W3, b3, out, G);
    }
}

// Round 8
// 1481.516 us; speedup vs baseline: 1.6443x; 1.0784x over previous
//
#include <hip/hip_runtime.h>
#include <hip/hip_fp16.h>

#define NPG 38
#define HEAD_BLK 256
#define SHIFT 13
#define SLICE (1 << SHIFT)        // 8192 nodes per dst-bucket (32KB LDS in binB)
#define DBMAX 640                 // max dst buckets
#define NSB 8                     // src super-buckets (== XCD count)
#define K1_NB 1024
#define P1_NB 4096
#define P1_THR 512
#define P1_QPB 3072               // max quads per P1 block (LDS stash bound)
#define P2_CHUNK 4096             // records per P2 block (32KB LDS stash)
#define P2_THR 512

typedef int      v4i __attribute__((ext_vector_type(4)));
typedef float    v4f __attribute__((ext_vector_type(4)));
typedef unsigned v2u __attribute__((ext_vector_type(2)));

static inline __device__ unsigned short f2h(float f) {
    return __half_as_ushort(__float2half(f));
}
static inline __device__ float h2f(unsigned short b) {
    return __half2float(__ushort_as_half(b));
}

// ---------------------------------------------------------------------------
// K1: global histograms — dst-bucket counts and src-super counts, one pass.
// ---------------------------------------------------------------------------
__global__ __launch_bounds__(512) void k_count(
    const int* __restrict__ src, const int* __restrict__ dst,
    int nquads, int qpb, int DB, int sbsz,
    int* __restrict__ gcntD, int* __restrict__ gcnt8)
{
    __shared__ int hD[DBMAX];
    __shared__ int h8[NSB];
    for (int i = threadIdx.x; i < DB; i += 512) hD[i] = 0;
    if (threadIdx.x < NSB) h8[threadIdx.x] = 0;
    __syncthreads();
    const int q0 = blockIdx.x * qpb;
    const int q1 = min(q0 + qpb, nquads);
    const v4i* s4 = (const v4i*)src;
    const v4i* d4 = (const v4i*)dst;
    for (int q = q0 + threadIdx.x; q < q1; q += 512) {
        v4i s = __builtin_nontemporal_load(s4 + q);
        v4i d = __builtin_nontemporal_load(d4 + q);
        atomicAdd(&h8[s.x / sbsz], 1);
        atomicAdd(&h8[s.y / sbsz], 1);
        atomicAdd(&h8[s.z / sbsz], 1);
        atomicAdd(&h8[s.w / sbsz], 1);
        atomicAdd(&hD[d.x >> SHIFT], 1);
        atomicAdd(&hD[d.y >> SHIFT], 1);
        atomicAdd(&hD[d.z >> SHIFT], 1);
        atomicAdd(&hD[d.w >> SHIFT], 1);
    }
    __syncthreads();
    for (int i = threadIdx.x; i < DB; i += 512) if (hD[i]) atomicAdd(&gcntD[i], hD[i]);
    if (threadIdx.x < NSB && h8[threadIdx.x]) atomicAdd(&gcnt8[threadIdx.x], h8[threadIdx.x]);
}

// ---------------------------------------------------------------------------
// K2: exclusive scans -> bases + live cursors (single thread; DB+8 elements)
// ---------------------------------------------------------------------------
__global__ void k_scan_init(
    const int* __restrict__ gcntD, const int* __restrict__ gcnt8, int DB,
    int* __restrict__ bbaseD, int* __restrict__ gcurD,
    int* __restrict__ bbase8, int* __restrict__ gcur8)
{
    if (threadIdx.x == 0 && blockIdx.x == 0) {
        int run = 0;
        for (int i = 0; i < DB; ++i) { bbaseD[i] = run; gcurD[i] = run; run += gcntD[i]; }
        bbaseD[DB] = run;
        run = 0;
        for (int i = 0; i < NSB; ++i) { bbase8[i] = run; gcur8[i] = run; run += gcnt8[i]; }
        bbase8[NSB] = run;
    }
}

// ---------------------------------------------------------------------------
// P1: route edges into 8 src-super segments. Record = 8B:
//   lo = (src_local[15:0] << 16) | fp16(theta),  hi = dst | (src_local[19:16] << 23)
// src quads stashed in LDS (pass A counts, pass B emits; no re-read).
// Only 8 cursors -> stores near-coalesced within segments.
// ---------------------------------------------------------------------------
__global__ __launch_bounds__(P1_THR) void k_p1(
    const int* __restrict__ src, const int* __restrict__ dst,
    const float* __restrict__ ea,
    const float* __restrict__ w_edge, const float* __restrict__ b_edge,
    int nquads, int qpb, int sbsz,
    int* __restrict__ gcur8, v2u* __restrict__ recs)
{
    __shared__ v4i stash[P1_QPB];
    __shared__ int h8[NSB];
    __shared__ int cur8[NSB];
    const int q0 = blockIdx.x * qpb;
    const int q1 = min(q0 + qpb, nquads);
    const int nq = q1 - q0;
    if (nq <= 0) return;
    if (threadIdx.x < NSB) h8[threadIdx.x] = 0;
    __syncthreads();
    const v4i* s4 = (const v4i*)src;
    for (int j = threadIdx.x; j < nq; j += P1_THR) {
        v4i s = __builtin_nontemporal_load(s4 + q0 + j);
        stash[j] = s;
        atomicAdd(&h8[s.x / sbsz], 1);
        atomicAdd(&h8[s.y / sbsz], 1);
        atomicAdd(&h8[s.z / sbsz], 1);
        atomicAdd(&h8[s.w / sbsz], 1);
    }
    __syncthreads();
    if (threadIdx.x < NSB)
        cur8[threadIdx.x] = atomicAdd(&gcur8[threadIdx.x], h8[threadIdx.x]);
    __syncthreads();
    const float we = w_edge[0], be = b_edge[0];
    const v4i* d4 = (const v4i*)dst;
    const v4f* e4 = (const v4f*)ea;
    for (int j = threadIdx.x; j < nq; j += P1_THR) {
        v4i s = stash[j];
        v4i d = __builtin_nontemporal_load(d4 + q0 + j);
        v4f e = __builtin_nontemporal_load(e4 + q0 + j);
        #pragma unroll
        for (int k = 0; k < 4; ++k) {
            int sv = (k == 0) ? s.x : (k == 1) ? s.y : (k == 2) ? s.z : s.w;
            int dv = (k == 0) ? d.x : (k == 1) ? d.y : (k == 2) ? d.z : d.w;
            float ev = (k == 0) ? e.x : (k == 1) ? e.y : (k == 2) ? e.z : e.w;
            int sb = sv / sbsz;
            int sl = sv - sb * sbsz;
            unsigned short tb = f2h(fmaf(ev, we, be));
            int p = atomicAdd(&cur8[sb], 1);
            v2u r;
            r.x = ((unsigned)(sl & 0xFFFF) << 16) | (unsigned)tb;
            r.y = (unsigned)dv | ((unsigned)(sl >> 16) << 23);
            recs[p] = r;
        }
    }
}

// ---------------------------------------------------------------------------
// P2: per src-super chunk. sb = blockIdx&7 -> all blocks of a super-bucket run
// on one XCD; its 2.5MB x-slice stays L2-resident. Chunk staged in LDS;
// dst-bucket space reserved via global-atomic cursors; emits packed 4B pairs
// (dst_local<<16 | fp16(msg)).
// ---------------------------------------------------------------------------
__global__ __launch_bounds__(P2_THR) void k_p2(
    const v2u* __restrict__ recs, const float* __restrict__ x,
    const int* __restrict__ bbase8, int sbsz, int DB,
    int* __restrict__ gcurD, unsigned* __restrict__ pairs)
{
    const int sb = blockIdx.x & 7;
    const int c  = blockIdx.x >> 3;
    const int seg0 = bbase8[sb], seg1 = bbase8[sb + 1];
    const int start = seg0 + c * P2_CHUNK;
    if (start >= seg1) return;
    const int end = min(start + P2_CHUNK, seg1);
    const int n = end - start;

    __shared__ v2u stash[P2_CHUNK];
    __shared__ int hD[DBMAX];
    __shared__ int cur[DBMAX];
    for (int i = threadIdx.x; i < DB; i += P2_THR) hD[i] = 0;
    __syncthreads();
    for (int i = threadIdx.x; i < n; i += P2_THR) {
        v2u r = __builtin_nontemporal_load(recs + start + i);
        stash[i] = r;
        atomicAdd(&hD[(r.y & 0x7FFFFFu) >> SHIFT], 1);
    }
    __syncthreads();
    for (int i = threadIdx.x; i < DB; i += P2_THR) {
        int cnt = hD[i];
        cur[i] = cnt ? atomicAdd(&gcurD[i], cnt) : 0;
    }
    __syncthreads();

    const float* xs = x + (size_t)sb * sbsz;
    int i = threadIdx.x;
    for (; i + P2_THR < n; i += 2 * P2_THR) {
        v2u r0 = stash[i];
        v2u r1 = stash[i + P2_THR];
        int sl0 = (int)(r0.x >> 16) | (int)((r0.y >> 23) << 16);
        int sl1 = (int)(r1.x >> 16) | (int)((r1.y >> 23) << 16);
        float x0 = xs[sl0];
        float x1 = xs[sl1];
        {
            unsigned d = r0.y & 0x7FFFFFu;
            float m = x0 * h2f((unsigned short)(r0.x & 0xFFFFu));
            int p = atomicAdd(&cur[d >> SHIFT], 1);
            pairs[p] = ((d & (SLICE - 1)) << 16) | (unsigned)f2h(m);
        }
        {
            unsigned d = r1.y & 0x7FFFFFu;
            float m = x1 * h2f((unsigned short)(r1.x & 0xFFFFu));
            int p = atomicAdd(&cur[d >> SHIFT], 1);
            pairs[p] = ((d & (SLICE - 1)) << 16) | (unsigned)f2h(m);
        }
    }
    if (i < n) {
        v2u r = stash[i];
        int sl = (int)(r.x >> 16) | (int)((r.y >> 23) << 16);
        float xv = xs[sl];
        unsigned d = r.y & 0x7FFFFFu;
        float m = xv * h2f((unsigned short)(r.x & 0xFFFFu));
        int p = atomicAdd(&cur[d >> SHIFT], 1);
        pairs[p] = ((d & (SLICE - 1)) << 16) | (unsigned)f2h(m);
    }
}

// ---------------------------------------------------------------------------
// Mid-fallback: dst-binning with gather (reservation-based, no histM), used
// when ws can't hold the 8B record array.
// ---------------------------------------------------------------------------
__global__ __launch_bounds__(512) void k_binA_resv(
    const float* __restrict__ x,
    const int* __restrict__ src, const int* __restrict__ dst,
    const float* __restrict__ ea,
    const float* __restrict__ w_edge, const float* __restrict__ b_edge,
    int nquads, int qpb, int DB,
    int* __restrict__ gcurD, unsigned* __restrict__ pairs)
{
    __shared__ int hD[DBMAX];
    __shared__ int cur[DBMAX];
    const int q0 = blockIdx.x * qpb;
    const int q1 = min(q0 + qpb, nquads);
    for (int i = threadIdx.x; i < DB; i += 512) hD[i] = 0;
    __syncthreads();
    const v4i* s4 = (const v4i*)src;
    const v4i* d4 = (const v4i*)dst;
    const v4f* e4 = (const v4f*)ea;
    for (int q = q0 + threadIdx.x; q < q1; q += 512) {
        v4i d = d4[q];
        atomicAdd(&hD[d.x >> SHIFT], 1);
        atomicAdd(&hD[d.y >> SHIFT], 1);
        atomicAdd(&hD[d.z >> SHIFT], 1);
        atomicAdd(&hD[d.w >> SHIFT], 1);
    }
    __syncthreads();
    for (int i = threadIdx.x; i < DB; i += 512) {
        int cnt = hD[i];
        cur[i] = cnt ? atomicAdd(&gcurD[i], cnt) : 0;
    }
    __syncthreads();
    const float we = w_edge[0], be = b_edge[0];
    for (int q = q0 + threadIdx.x; q < q1; q += 512) {
        v4i s = __builtin_nontemporal_load(s4 + q);
        v4i d = d4[q];
        v4f e = __builtin_nontemporal_load(e4 + q);
        #pragma unroll
        for (int k = 0; k < 4; ++k) {
            int sv = (k == 0) ? s.x : (k == 1) ? s.y : (k == 2) ? s.z : s.w;
            unsigned dv = (unsigned)((k == 0) ? d.x : (k == 1) ? d.y : (k == 2) ? d.z : d.w);
            float ev = (k == 0) ? e.x : (k == 1) ? e.y : (k == 2) ? e.z : e.w;
            float m = x[sv] * fmaf(ev, we, be);
            int p = atomicAdd(&cur[dv >> SHIFT], 1);
            pairs[p] = ((dv & (SLICE - 1)) << 16) | (unsigned)f2h(m);
        }
    }
}

// ---------------------------------------------------------------------------
// P3: per-bucket LDS accumulation of packed pairs + root transform -> nodes
// ---------------------------------------------------------------------------
__global__ __launch_bounds__(1024) void k_binB(
    const unsigned* __restrict__ pairs,
    const int* __restrict__ bbaseD,
    const float* __restrict__ x,
    const float* __restrict__ w_root, const float* __restrict__ b_conv,
    float* __restrict__ nodes, int N)
{
    __shared__ float slice[SLICE];               // 32768 B
    const int b = blockIdx.x;
    for (int i = threadIdx.x; i < SLICE; i += 1024) slice[i] = 0.0f;
    __syncthreads();
    const int p0 = bbaseD[b];
    const int p1 = bbaseD[b + 1];
    for (int i = p0 + threadIdx.x; i < p1; i += 1024) {
        unsigned p = __builtin_nontemporal_load(pairs + i);
        atomicAdd(&slice[p >> 16], h2f((unsigned short)(p & 0xFFFFu)));
    }
    __syncthreads();
    const float wr = w_root[0], bc = b_conv[0];
    const int gbase = b << SHIFT;
    for (int i = threadIdx.x; i < SLICE; i += 1024) {
        int gi = gbase + i;
        if (gi < N) nodes[gi] = slice[i] + fmaf(__builtin_nontemporal_load(x + gi), wr, bc);
    }
}

// ---------------------------------------------------------------------------
// Bottom fallback: global atomics
// ---------------------------------------------------------------------------
__global__ __launch_bounds__(256) void edge_kernel_atomic(
    const float* __restrict__ x,
    const int*   __restrict__ src, const int* __restrict__ dst,
    const float* __restrict__ ea,
    const float* __restrict__ w_edge, const float* __restrict__ b_edge,
    float* __restrict__ agg, int E)
{
    const float we = w_edge[0], be = b_edge[0];
    int tid = blockIdx.x * blockDim.x + threadIdx.x;
    int stride = gridDim.x * blockDim.x;
    for (int i = tid; i < E; i += stride)
        atomicAdd(&agg[dst[i]], x[src[i]] * fmaf(ea[i], we, be));
}

__global__ __launch_bounds__(256) void finalize_nodes(
    const float* __restrict__ x, const float* __restrict__ agg,
    const float* __restrict__ w_root, const float* __restrict__ b_conv,
    float* __restrict__ nodes, int N)
{
    const float wr = w_root[0], bc = b_conv[0];
    int i = blockIdx.x * blockDim.x + threadIdx.x;
    int stride = gridDim.x * blockDim.x;
    for (; i < N; i += stride) nodes[i] = agg[i] + fmaf(x[i], wr, bc);
}

// ---------------------------------------------------------------------------
// Head MLP over per-graph node vectors + softmax
// ---------------------------------------------------------------------------
__global__ __launch_bounds__(HEAD_BLK) void head_kernel(
    const float* __restrict__ nodes,
    const float* __restrict__ W1, const float* __restrict__ b1,
    const float* __restrict__ W2, const float* __restrict__ b2,
    const float* __restrict__ W3, const float* __restrict__ b3,
    float* __restrict__ out, int G)
{
    __shared__ float s_nodes[HEAD_BLK * NPG];   // 38912 B
    __shared__ float s_W1[NPG * 4];
    __shared__ float s_W2[4 * 4];
    __shared__ float s_W3[4 * 12];
    __shared__ float s_b1[4];
    __shared__ float s_b2[4];
    __shared__ float s_b3[12];

    const int tid = threadIdx.x;
    if (tid < NPG * 4) s_W1[tid] = W1[tid];
    if (tid >= 160 && tid < 176) s_W2[tid - 160] = W2[tid - 160];
    if (tid >= 176 && tid < 224) s_W3[tid - 176] = W3[tid - 176];
    if (tid >= 224 && tid < 228) s_b1[tid - 224] = b1[tid - 224];
    if (tid >= 228 && tid < 232) s_b2[tid - 228] = b2[tid - 228];
    if (tid >= 232 && tid < 244) s_b3[tid - 232] = b3[tid - 232];

    const int g0 = blockIdx.x * HEAD_BLK;
    const size_t ebase = (size_t)g0 * NPG;
    const int nelem = HEAD_BLK * NPG;
    const int avail = min(nelem, (G - g0) * NPG);
    for (int i = tid; i < avail; i += HEAD_BLK) s_nodes[i] = nodes[ebase + i];
    __syncthreads();

    const int g = g0 + tid;
    if (g >= G) return;
    const float* nd = &s_nodes[tid * NPG];

    float h1[4];
    #pragma unroll
    for (int k = 0; k < 4; ++k) h1[k] = s_b1[k];
    #pragma unroll
    for (int j = 0; j < NPG; ++j) {
        const float nj = nd[j];
        #pragma unroll
        for (int k = 0; k < 4; ++k) h1[k] = fmaf(nj, s_W1[j * 4 + k], h1[k]);
    }
    #pragma unroll
    for (int k = 0; k < 4; ++k) h1[k] = h1[k] >= 0.0f ? h1[k] : 0.01f * h1[k];

    float h2[4];
    #pragma unroll
    for (int k = 0; k < 4; ++k) {
        float a = s_b2[k];
        #pragma unroll
        for (int j = 0; j < 4; ++j) a = fmaf(h1[j], s_W2[j * 4 + k], a);
        h2[k] = a >= 0.0f ? a : 0.01f * a;
    }

    float h3[12];
    #pragma unroll
    for (int k = 0; k < 12; ++k) {
        float a = s_b3[k];
        #pragma unroll
        for (int j = 0; j < 4; ++j) a = fmaf(h2[j], s_W3[j * 12 + k], a);
        h3[k] = a >= 0.0f ? a : 0.01f * a;
    }

    float m = h3[0];
    #pragma unroll
    for (int k = 1; k < 12; ++k) m = fmaxf(m, h3[k]);
    float sum = 0.0f;
    #pragma unroll
    for (int k = 0; k < 12; ++k) { h3[k] = expf(h3[k] - m); sum += h3[k]; }
    const float inv = 1.0f / sum;

    float4* o = reinterpret_cast<float4*>(out + (size_t)g * 12);
    o[0] = make_float4(h3[0] * inv, h3[1] * inv, h3[2]  * inv, h3[3]  * inv);
    o[1] = make_float4(h3[4] * inv, h3[5] * inv, h3[6]  * inv, h3[7]  * inv);
    o[2] = make_float4(h3[8] * inv, h3[9] * inv, h3[10] * inv, h3[11] * inv);
}

extern "C" void kernel_launch(void* const* d_in, const int* in_sizes, int n_in,
                              void* d_out, int out_size, void* d_ws, size_t ws_size,
                              hipStream_t stream)
{
    const float* x      = (const float*)d_in[0];
    const int*   eidx   = (const int*)  d_in[1];
    const float* ea     = (const float*)d_in[2];
    const float* w_edge = (const float*)d_in[3];
    const float* b_edge = (const float*)d_in[4];
    const float* w_root = (const float*)d_in[5];
    const float* b_conv = (const float*)d_in[6];
    const float* W1 = (const float*)d_in[7];
    const float* b1 = (const float*)d_in[8];
    const float* W2 = (const float*)d_in[9];
    const float* b2 = (const float*)d_in[10];
    const float* W3 = (const float*)d_in[11];
    const float* b3 = (const float*)d_in[12];
    float* out = (float*)d_out;

    const int N = in_sizes[0];
    const int E = in_sizes[2];
    const int G = N / NPG;
    const int* src = eidx;
    const int* dst = eidx + E;
    const int nquads = E / 4;
    const int DB = (N + SLICE - 1) >> SHIFT;

    const int hblocks = (G + HEAD_BLK - 1) / HEAD_BLK;
    char* ws = (char*)d_ws;

    // meta region (ints): gcntD[DBMAX], gcnt8[8] | bbaseD[DBMAX+1], gcurD[DBMAX],
    //                     bbase8[9], gcur8[8]
    const size_t META_INTS = DBMAX + 8 + (DBMAX + 1) + DBMAX + 9 + 8;

    // ---- path selection ----
    const bool quadok = (E % 4) == 0 && DB <= DBMAX && DB >= 1;
    const int  sbsz   = (N % NSB == 0) ? (N / NSB) : 0;
    const int  qpb1   = (nquads + P1_NB - 1) / P1_NB;

    // v3 layout: recs (E*8) | pairs (E*4) | nodes (N*4) | meta
    size_t off_pairs_v3 = (size_t)E * 8;
    size_t off_nodes_v3 = off_pairs_v3 + (size_t)E * 4;
    size_t off_meta_v3  = off_nodes_v3 + (size_t)N * 4;
    size_t need_v3      = off_meta_v3 + META_INTS * 4;

    // mid layout: pairs (E*4) | nodes | meta
    size_t off_nodes_mid = (size_t)E * 4;
    size_t off_meta_mid  = off_nodes_mid + (size_t)N * 4;
    size_t need_mid      = off_meta_mid + META_INTS * 4;

    if (quadok && sbsz > 0 && qpb1 <= P1_QPB && need_v3 <= ws_size) {
        v2u*      recs  = (v2u*)ws;
        unsigned* pairs = (unsigned*)(ws + off_pairs_v3);
        float*    nodes = (float*)(ws + off_nodes_v3);
        int*      meta  = (int*)(ws + off_meta_v3);
        int* gcntD  = meta;
        int* gcnt8  = meta + DBMAX;
        int* bbaseD = meta + DBMAX + 8;
        int* gcurD  = bbaseD + DBMAX + 1;
        int* bbase8 = gcurD + DBMAX;
        int* gcur8  = bbase8 + 9;

        hipMemsetAsync(gcntD, 0, (DBMAX + 8) * sizeof(int), stream);

        const int qpbK1 = (nquads + K1_NB - 1) / K1_NB;
        k_count<<<K1_NB, 512, 0, stream>>>(src, dst, nquads, qpbK1, DB, sbsz,
                                           gcntD, gcnt8);
        k_scan_init<<<1, 64, 0, stream>>>(gcntD, gcnt8, DB, bbaseD, gcurD,
                                          bbase8, gcur8);
        k_p1<<<P1_NB, P1_THR, 0, stream>>>(src, dst, ea, w_edge, b_edge,
                                           nquads, qpb1, sbsz, gcur8, recs);
        const int cpb = (E + P2_CHUNK - 1) / P2_CHUNK;   // covers any skew
        k_p2<<<8 * cpb, P2_THR, 0, stream>>>(recs, x, bbase8, sbsz, DB,
                                             gcurD, pairs);
        k_binB<<<DB, 1024, 0, stream>>>(pairs, bbaseD, x, w_root, b_conv,
                                        nodes, N);
        head_kernel<<<hblocks, HEAD_BLK, 0, stream>>>(nodes, W1, b1, W2, b2,
                                                      W3, b3, out, G);
    } else if (quadok && need_mid <= ws_size) {
        unsigned* pairs = (unsigned*)ws;
        float*    nodes = (float*)(ws + off_nodes_mid);
        int*      meta  = (int*)(ws + off_meta_mid);
        int* gcntD  = meta;
        int* gcnt8  = meta + DBMAX;
        int* bbaseD = meta + DBMAX + 8;
        int* gcurD  = bbaseD + DBMAX + 1;
        int* bbase8 = gcurD + DBMAX;
        int* gcur8  = bbase8 + 9;

        hipMemsetAsync(gcntD, 0, (DBMAX + 8) * sizeof(int), stream);
        const int sb_safe = (sbsz > 0) ? sbsz : N;   // unused result, avoid /0
        const int qpbK1 = (nquads + K1_NB - 1) / K1_NB;
        k_count<<<K1_NB, 512, 0, stream>>>(src, dst, nquads, qpbK1, DB, sb_safe,
                                           gcntD, gcnt8);
        k_scan_init<<<1, 64, 0, stream>>>(gcntD, gcnt8, DB, bbaseD, gcurD,
                                          bbase8, gcur8);
        const int NBm = 2048;
        const int qpbm = (nquads + NBm - 1) / NBm;
        k_binA_resv<<<NBm, 512, 0, stream>>>(x, src, dst, ea, w_edge, b_edge,
                                             nquads, qpbm, DB, gcurD, pairs);
        k_binB<<<DB, 1024, 0, stream>>>(pairs, bbaseD, x, w_root, b_conv,
                                        nodes, N);
        head_kernel<<<hblocks, HEAD_BLK, 0, stream>>>(nodes, W1, b1, W2, b2,
                                                      W3, b3, out, G);
    } else {
        float* agg   = (float*)d_ws;
        float* nodes = agg + N;
        hipMemsetAsync(agg, 0, (size_t)N * sizeof(float), stream);
        edge_kernel_atomic<<<2048, 256, 0, stream>>>(x, src, dst, ea, w_edge,
                                                     b_edge, agg, E);
        finalize_nodes<<<2048, 256, 0, stream>>>(x, agg, w_root, b_conv, nodes, N);
        head_kernel<<<hblocks, HEAD_BLK, 0, stream>>>(nodes, W1, b1, W2, b2,
                                                      W3, b3, out, G);
    }
}

// Round 9
// 1168.176 us; speedup vs baseline: 2.0854x; 1.2682x over previous
//
#include <hip/hip_runtime.h>
#include <hip/hip_fp16.h>

#define NPG 38
#define HEAD_BLK 256
#define SHIFT 14
#define SLICE (1 << SHIFT)        // 16384 nodes per dst-bucket (64KB LDS in binB)
#define DBMAX 320                 // max dst buckets
#define NSB 8                     // src super-buckets (== XCD count)
#define K1_NB 1024
#define P1_NB 4096
#define P1_THR 512
#define P1_QPB 3072               // max quads per P1 block (LDS stash bound)
#define CH 8192                   // records per P2 chunk (32KB LDS pairbuf)
#define P2_THR 512

typedef int      v4i __attribute__((ext_vector_type(4)));
typedef float    v4f __attribute__((ext_vector_type(4)));
typedef unsigned v2u __attribute__((ext_vector_type(2)));

static inline __device__ unsigned short f2h(float f) {
    return __half_as_ushort(__float2half(f));
}
static inline __device__ float h2f(unsigned short b) {
    return __half2float(__ushort_as_half(b));
}

// ---------------------------------------------------------------------------
// K1: src super-bucket histogram only (dst histogram is fused into P1)
// ---------------------------------------------------------------------------
__global__ __launch_bounds__(512) void k_count8(
    const int* __restrict__ src, int nquads, int qpb, int sbsz,
    int* __restrict__ gcnt8)
{
    __shared__ int h8[NSB];
    if (threadIdx.x < NSB) h8[threadIdx.x] = 0;
    __syncthreads();
    const int q0 = blockIdx.x * qpb;
    const int q1 = min(q0 + qpb, nquads);
    const v4i* s4 = (const v4i*)src;
    for (int q = q0 + threadIdx.x; q < q1; q += 512) {
        v4i s = __builtin_nontemporal_load(s4 + q);
        atomicAdd(&h8[s.x / sbsz], 1);
        atomicAdd(&h8[s.y / sbsz], 1);
        atomicAdd(&h8[s.z / sbsz], 1);
        atomicAdd(&h8[s.w / sbsz], 1);
    }
    __syncthreads();
    if (threadIdx.x < NSB && h8[threadIdx.x])
        atomicAdd(&gcnt8[threadIdx.x], h8[threadIdx.x]);
}

// scan of the 8 super counts
__global__ void k_scan8(const int* __restrict__ gcnt8,
                        int* __restrict__ bbase8, int* __restrict__ gcur8)
{
    if (threadIdx.x == 0 && blockIdx.x == 0) {
        int run = 0;
        for (int i = 0; i < NSB; ++i) { bbase8[i] = run; gcur8[i] = run; run += gcnt8[i]; }
        bbase8[NSB] = run;
    }
}

// scan of dst-bucket counts (after P1 fills gcntD)
__global__ void k_scanD(const int* __restrict__ gcntD, int DB,
                        int* __restrict__ bbaseD, int* __restrict__ gcurD)
{
    if (threadIdx.x == 0 && blockIdx.x == 0) {
        int run = 0;
        for (int i = 0; i < DB; ++i) { bbaseD[i] = run; gcurD[i] = run; run += gcntD[i]; }
        bbaseD[DB] = run;
    }
}

// ---------------------------------------------------------------------------
// P1: route edges into 8 src-super segments; also accumulate dst-bucket
// histogram (free: dst already in registers). Record = 8B:
//   lo = (src_local[15:0] << 16) | fp16(theta), hi = dst | (src_local[19:16]<<23)
// ---------------------------------------------------------------------------
__global__ __launch_bounds__(P1_THR) void k_p1(
    const int* __restrict__ src, const int* __restrict__ dst,
    const float* __restrict__ ea,
    const float* __restrict__ w_edge, const float* __restrict__ b_edge,
    int nquads, int qpb, int sbsz, int DB,
    int* __restrict__ gcur8, int* __restrict__ gcntD,
    v2u* __restrict__ recs)
{
    __shared__ v4i stash[P1_QPB];
    __shared__ int h8[NSB];
    __shared__ int cur8[NSB];
    __shared__ int hD[DBMAX];
    const int q0 = blockIdx.x * qpb;
    const int q1 = min(q0 + qpb, nquads);
    const int nq = q1 - q0;
    if (nq <= 0) return;
    if (threadIdx.x < NSB) h8[threadIdx.x] = 0;
    for (int i = threadIdx.x; i < DB; i += P1_THR) hD[i] = 0;
    __syncthreads();
    const v4i* s4 = (const v4i*)src;
    for (int j = threadIdx.x; j < nq; j += P1_THR) {
        v4i s = __builtin_nontemporal_load(s4 + q0 + j);
        stash[j] = s;
        atomicAdd(&h8[s.x / sbsz], 1);
        atomicAdd(&h8[s.y / sbsz], 1);
        atomicAdd(&h8[s.z / sbsz], 1);
        atomicAdd(&h8[s.w / sbsz], 1);
    }
    __syncthreads();
    if (threadIdx.x < NSB)
        cur8[threadIdx.x] = atomicAdd(&gcur8[threadIdx.x], h8[threadIdx.x]);
    __syncthreads();
    const float we = w_edge[0], be = b_edge[0];
    const v4i* d4 = (const v4i*)dst;
    const v4f* e4 = (const v4f*)ea;
    for (int j = threadIdx.x; j < nq; j += P1_THR) {
        v4i s = stash[j];
        v4i d = __builtin_nontemporal_load(d4 + q0 + j);
        v4f e = __builtin_nontemporal_load(e4 + q0 + j);
        #pragma unroll
        for (int k = 0; k < 4; ++k) {
            int sv = (k == 0) ? s.x : (k == 1) ? s.y : (k == 2) ? s.z : s.w;
            int dv = (k == 0) ? d.x : (k == 1) ? d.y : (k == 2) ? d.z : d.w;
            float ev = (k == 0) ? e.x : (k == 1) ? e.y : (k == 2) ? e.z : e.w;
            int sb = sv / sbsz;
            int sl = sv - sb * sbsz;
            unsigned short tb = f2h(fmaf(ev, we, be));
            atomicAdd(&hD[dv >> SHIFT], 1);
            int p = atomicAdd(&cur8[sb], 1);
            v2u r;
            r.x = ((unsigned)(sl & 0xFFFF) << 16) | (unsigned)tb;
            r.y = (unsigned)dv | ((unsigned)(sl >> 16) << 23);
            recs[p] = r;
        }
    }
    __syncthreads();
    for (int i = threadIdx.x; i < DB; i += P1_THR)
        if (hD[i]) atomicAdd(&gcntD[i], hD[i]);
}

// ---------------------------------------------------------------------------
// P2: per src-super chunk (sb = blockIdx&7 -> XCD affinity, x slice L2-hot).
// Pass A: hist chunk's dst buckets. Reserve global ranges. LDS counting sort
// into pairbuf. Pass C: per-wave coalesced write-out of each bucket's run.
// Grid-strides over chunks for distribution-independent correctness.
// ---------------------------------------------------------------------------
__global__ __launch_bounds__(P2_THR) void k_p2(
    const v2u* __restrict__ recs, const float* __restrict__ x,
    const int* __restrict__ bbase8, int sbsz, int DB, int cpb,
    int* __restrict__ gcurD, unsigned* __restrict__ pairs)
{
    __shared__ unsigned pairbuf[CH];            // 32768 B
    __shared__ int hD[DBMAX];
    __shared__ int lofs[DBMAX];
    __shared__ int lcur[DBMAX];
    __shared__ int gofs[DBMAX];

    const int sb = blockIdx.x & 7;
    const int c0 = blockIdx.x >> 3;
    const int seg0 = bbase8[sb], seg1 = bbase8[sb + 1];
    const float* xs = x + (size_t)sb * sbsz;
    const int tid = threadIdx.x;
    const int wid = tid >> 6, lane = tid & 63;

    for (int cc = c0; ; cc += cpb) {
        const int start = seg0 + cc * CH;
        if (start >= seg1) break;
        const int n = min(CH, seg1 - start);

        for (int i = tid; i < DB; i += P2_THR) hD[i] = 0;
        __syncthreads();
        // pass A: histogram
        for (int i = tid; i < n; i += P2_THR) {
            v2u r = recs[start + i];
            atomicAdd(&hD[(r.y & 0x7FFFFFu) >> SHIFT], 1);
        }
        __syncthreads();
        // reserve global ranges + local exclusive scan
        for (int i = tid; i < DB; i += P2_THR) {
            int cnt = hD[i];
            gofs[i] = cnt ? atomicAdd(&gcurD[i], cnt) : 0;
        }
        if (tid == 0) {
            int run = 0;
            for (int i = 0; i < DB; ++i) { lofs[i] = run; run += hD[i]; }
        }
        __syncthreads();
        for (int i = tid; i < DB; i += P2_THR) lcur[i] = lofs[i];
        __syncthreads();
        // pass B: gather x (L2-resident slice), compute msg, LDS scatter-sort
        for (int i = tid; i < n; i += P2_THR) {
            v2u r = recs[start + i];                  // L2-hot re-read
            int sl = (int)(r.x >> 16) | (int)((r.y >> 23) << 16);
            unsigned d = r.y & 0x7FFFFFu;
            float m = xs[sl] * h2f((unsigned short)(r.x & 0xFFFFu));
            int li = atomicAdd(&lcur[d >> SHIFT], 1);
            pairbuf[li] = ((d & (SLICE - 1)) << 16) | (unsigned)f2h(m);
        }
        __syncthreads();
        // pass C: per-wave coalesced run write-out
        for (int b = wid; b < DB; b += P2_THR / 64) {
            const int L = hD[b], lo = lofs[b], go = gofs[b];
            for (int j = lane; j < L; j += 64)
                pairs[go + j] = pairbuf[lo + j];
        }
        __syncthreads();
    }
}

// ---------------------------------------------------------------------------
// Mid-fallback: dst-binning with gather (reservation-based)
// ---------------------------------------------------------------------------
__global__ __launch_bounds__(512) void k_count_mid(
    const int* __restrict__ dst, int nquads, int qpb, int DB,
    int* __restrict__ gcntD)
{
    __shared__ int hD[DBMAX];
    for (int i = threadIdx.x; i < DB; i += 512) hD[i] = 0;
    __syncthreads();
    const int q0 = blockIdx.x * qpb;
    const int q1 = min(q0 + qpb, nquads);
    const v4i* d4 = (const v4i*)dst;
    for (int q = q0 + threadIdx.x; q < q1; q += 512) {
        v4i d = __builtin_nontemporal_load(d4 + q);
        atomicAdd(&hD[d.x >> SHIFT], 1);
        atomicAdd(&hD[d.y >> SHIFT], 1);
        atomicAdd(&hD[d.z >> SHIFT], 1);
        atomicAdd(&hD[d.w >> SHIFT], 1);
    }
    __syncthreads();
    for (int i = threadIdx.x; i < DB; i += 512)
        if (hD[i]) atomicAdd(&gcntD[i], hD[i]);
}

__global__ __launch_bounds__(512) void k_binA_resv(
    const float* __restrict__ x,
    const int* __restrict__ src, const int* __restrict__ dst,
    const float* __restrict__ ea,
    const float* __restrict__ w_edge, const float* __restrict__ b_edge,
    int nquads, int qpb, int DB,
    int* __restrict__ gcurD, unsigned* __restrict__ pairs)
{
    __shared__ int hD[DBMAX];
    __shared__ int cur[DBMAX];
    const int q0 = blockIdx.x * qpb;
    const int q1 = min(q0 + qpb, nquads);
    for (int i = threadIdx.x; i < DB; i += 512) hD[i] = 0;
    __syncthreads();
    const v4i* s4 = (const v4i*)src;
    const v4i* d4 = (const v4i*)dst;
    const v4f* e4 = (const v4f*)ea;
    for (int q = q0 + threadIdx.x; q < q1; q += 512) {
        v4i d = d4[q];
        atomicAdd(&hD[d.x >> SHIFT], 1);
        atomicAdd(&hD[d.y >> SHIFT], 1);
        atomicAdd(&hD[d.z >> SHIFT], 1);
        atomicAdd(&hD[d.w >> SHIFT], 1);
    }
    __syncthreads();
    for (int i = threadIdx.x; i < DB; i += 512) {
        int cnt = hD[i];
        cur[i] = cnt ? atomicAdd(&gcurD[i], cnt) : 0;
    }
    __syncthreads();
    const float we = w_edge[0], be = b_edge[0];
    for (int q = q0 + threadIdx.x; q < q1; q += 512) {
        v4i s = __builtin_nontemporal_load(s4 + q);
        v4i d = d4[q];
        v4f e = __builtin_nontemporal_load(e4 + q);
        #pragma unroll
        for (int k = 0; k < 4; ++k) {
            int sv = (k == 0) ? s.x : (k == 1) ? s.y : (k == 2) ? s.z : s.w;
            unsigned dv = (unsigned)((k == 0) ? d.x : (k == 1) ? d.y : (k == 2) ? d.z : d.w);
            float ev = (k == 0) ? e.x : (k == 1) ? e.y : (k == 2) ? e.z : e.w;
            float m = x[sv] * fmaf(ev, we, be);
            int p = atomicAdd(&cur[dv >> SHIFT], 1);
            pairs[p] = ((dv & (SLICE - 1)) << 16) | (unsigned)f2h(m);
        }
    }
}

// ---------------------------------------------------------------------------
// P3: per-bucket LDS accumulation of packed pairs + root transform -> nodes
// ---------------------------------------------------------------------------
__global__ __launch_bounds__(1024) void k_binB(
    const unsigned* __restrict__ pairs,
    const int* __restrict__ bbaseD,
    const float* __restrict__ x,
    const float* __restrict__ w_root, const float* __restrict__ b_conv,
    float* __restrict__ nodes, int N)
{
    __shared__ float slice[SLICE];               // 65536 B
    const int b = blockIdx.x;
    for (int i = threadIdx.x; i < SLICE; i += 1024) slice[i] = 0.0f;
    __syncthreads();
    const int p0 = bbaseD[b];
    const int p1 = bbaseD[b + 1];
    for (int i = p0 + threadIdx.x; i < p1; i += 1024) {
        unsigned p = __builtin_nontemporal_load(pairs + i);
        atomicAdd(&slice[p >> 16], h2f((unsigned short)(p & 0xFFFFu)));
    }
    __syncthreads();
    const float wr = w_root[0], bc = b_conv[0];
    const int gbase = b << SHIFT;
    for (int i = threadIdx.x; i < SLICE; i += 1024) {
        int gi = gbase + i;
        if (gi < N) nodes[gi] = slice[i] + fmaf(__builtin_nontemporal_load(x + gi), wr, bc);
    }
}

// ---------------------------------------------------------------------------
// Bottom fallback: global atomics
// ---------------------------------------------------------------------------
__global__ __launch_bounds__(256) void edge_kernel_atomic(
    const float* __restrict__ x,
    const int*   __restrict__ src, const int* __restrict__ dst,
    const float* __restrict__ ea,
    const float* __restrict__ w_edge, const float* __restrict__ b_edge,
    float* __restrict__ agg, int E)
{
    const float we = w_edge[0], be = b_edge[0];
    int tid = blockIdx.x * blockDim.x + threadIdx.x;
    int stride = gridDim.x * blockDim.x;
    for (int i = tid; i < E; i += stride)
        atomicAdd(&agg[dst[i]], x[src[i]] * fmaf(ea[i], we, be));
}

__global__ __launch_bounds__(256) void finalize_nodes(
    const float* __restrict__ x, const float* __restrict__ agg,
    const float* __restrict__ w_root, const float* __restrict__ b_conv,
    float* __restrict__ nodes, int N)
{
    const float wr = w_root[0], bc = b_conv[0];
    int i = blockIdx.x * blockDim.x + threadIdx.x;
    int stride = gridDim.x * blockDim.x;
    for (; i < N; i += stride) nodes[i] = agg[i] + fmaf(x[i], wr, bc);
}

// ---------------------------------------------------------------------------
// Head MLP over per-graph node vectors + softmax
// ---------------------------------------------------------------------------
__global__ __launch_bounds__(HEAD_BLK) void head_kernel(
    const float* __restrict__ nodes,
    const float* __restrict__ W1, const float* __restrict__ b1,
    const float* __restrict__ W2, const float* __restrict__ b2,
    const float* __restrict__ W3, const float* __restrict__ b3,
    float* __restrict__ out, int G)
{
    __shared__ float s_nodes[HEAD_BLK * NPG];   // 38912 B
    __shared__ float s_W1[NPG * 4];
    __shared__ float s_W2[4 * 4];
    __shared__ float s_W3[4 * 12];
    __shared__ float s_b1[4];
    __shared__ float s_b2[4];
    __shared__ float s_b3[12];

    const int tid = threadIdx.x;
    if (tid < NPG * 4) s_W1[tid] = W1[tid];
    if (tid >= 160 && tid < 176) s_W2[tid - 160] = W2[tid - 160];
    if (tid >= 176 && tid < 224) s_W3[tid - 176] = W3[tid - 176];
    if (tid >= 224 && tid < 228) s_b1[tid - 224] = b1[tid - 224];
    if (tid >= 228 && tid < 232) s_b2[tid - 228] = b2[tid - 228];
    if (tid >= 232 && tid < 244) s_b3[tid - 232] = b3[tid - 232];

    const int g0 = blockIdx.x * HEAD_BLK;
    const size_t ebase = (size_t)g0 * NPG;
    const int nelem = HEAD_BLK * NPG;
    const int avail = min(nelem, (G - g0) * NPG);
    for (int i = tid; i < avail; i += HEAD_BLK) s_nodes[i] = nodes[ebase + i];
    __syncthreads();

    const int g = g0 + tid;
    if (g >= G) return;
    const float* nd = &s_nodes[tid * NPG];

    float h1[4];
    #pragma unroll
    for (int k = 0; k < 4; ++k) h1[k] = s_b1[k];
    #pragma unroll
    for (int j = 0; j < NPG; ++j) {
        const float nj = nd[j];
        #pragma unroll
        for (int k = 0; k < 4; ++k) h1[k] = fmaf(nj, s_W1[j * 4 + k], h1[k]);
    }
    #pragma unroll
    for (int k = 0; k < 4; ++k) h1[k] = h1[k] >= 0.0f ? h1[k] : 0.01f * h1[k];

    float h2[4];
    #pragma unroll
    for (int k = 0; k < 4; ++k) {
        float a = s_b2[k];
        #pragma unroll
        for (int j = 0; j < 4; ++j) a = fmaf(h1[j], s_W2[j * 4 + k], a);
        h2[k] = a >= 0.0f ? a : 0.01f * a;
    }

    float h3[12];
    #pragma unroll
    for (int k = 0; k < 12; ++k) {
        float a = s_b3[k];
        #pragma unroll
        for (int j = 0; j < 4; ++j) a = fmaf(h2[j], s_W3[j * 12 + k], a);
        h3[k] = a >= 0.0f ? a : 0.01f * a;
    }

    float m = h3[0];
    #pragma unroll
    for (int k = 1; k < 12; ++k) m = fmaxf(m, h3[k]);
    float sum = 0.0f;
    #pragma unroll
    for (int k = 0; k < 12; ++k) { h3[k] = expf(h3[k] - m); sum += h3[k]; }
    const float inv = 1.0f / sum;

    float4* o = reinterpret_cast<float4*>(out + (size_t)g * 12);
    o[0] = make_float4(h3[0] * inv, h3[1] * inv, h3[2]  * inv, h3[3]  * inv);
    o[1] = make_float4(h3[4] * inv, h3[5] * inv, h3[6]  * inv, h3[7]  * inv);
    o[2] = make_float4(h3[8] * inv, h3[9] * inv, h3[10] * inv, h3[11] * inv);
}

extern "C" void kernel_launch(void* const* d_in, const int* in_sizes, int n_in,
                              void* d_out, int out_size, void* d_ws, size_t ws_size,
                              hipStream_t stream)
{
    const float* x      = (const float*)d_in[0];
    const int*   eidx   = (const int*)  d_in[1];
    const float* ea     = (const float*)d_in[2];
    const float* w_edge = (const float*)d_in[3];
    const float* b_edge = (const float*)d_in[4];
    const float* w_root = (const float*)d_in[5];
    const float* b_conv = (const float*)d_in[6];
    const float* W1 = (const float*)d_in[7];
    const float* b1 = (const float*)d_in[8];
    const float* W2 = (const float*)d_in[9];
    const float* b2 = (const float*)d_in[10];
    const float* W3 = (const float*)d_in[11];
    const float* b3 = (const float*)d_in[12];
    float* out = (float*)d_out;

    const int N = in_sizes[0];
    const int E = in_sizes[2];
    const int G = N / NPG;
    const int* src = eidx;
    const int* dst = eidx + E;
    const int nquads = E / 4;
    const int DB = (N + SLICE - 1) >> SHIFT;

    const int hblocks = (G + HEAD_BLK - 1) / HEAD_BLK;
    char* ws = (char*)d_ws;

    // meta ints: gcnt8[8], gcntD[DBMAX] | bbase8[9], gcur8[8],
    //            bbaseD[DBMAX+1], gcurD[DBMAX]
    const size_t META_INTS = 8 + DBMAX + 9 + 8 + (DBMAX + 1) + DBMAX;

    const bool quadok = (E % 4) == 0 && DB <= DBMAX && DB >= 1;
    const int  sbsz   = (N % NSB == 0) ? (N / NSB) : 0;
    const int  qpb1   = (nquads + P1_NB - 1) / P1_NB;

    // v3 layout: recs (E*8) | pairs (E*4) | nodes (N*4) | meta
    size_t off_pairs_v3 = (size_t)E * 8;
    size_t off_nodes_v3 = off_pairs_v3 + (size_t)E * 4;
    size_t off_meta_v3  = off_nodes_v3 + (size_t)N * 4;
    size_t need_v3      = off_meta_v3 + META_INTS * 4;

    // mid layout: pairs (E*4) | nodes | meta
    size_t off_nodes_mid = (size_t)E * 4;
    size_t off_meta_mid  = off_nodes_mid + (size_t)N * 4;
    size_t need_mid      = off_meta_mid + META_INTS * 4;

    if (quadok && sbsz > 0 && qpb1 <= P1_QPB && need_v3 <= ws_size) {
        v2u*      recs  = (v2u*)ws;
        unsigned* pairs = (unsigned*)(ws + off_pairs_v3);
        float*    nodes = (float*)(ws + off_nodes_v3);
        int*      meta  = (int*)(ws + off_meta_v3);
        int* gcnt8  = meta;
        int* gcntD  = meta + 8;
        int* bbase8 = meta + 8 + DBMAX;
        int* gcur8  = bbase8 + 9;
        int* bbaseD = gcur8 + 8;
        int* gcurD  = bbaseD + DBMAX + 1;

        hipMemsetAsync(meta, 0, (8 + DBMAX) * sizeof(int), stream);

        const int qpbK1 = (nquads + K1_NB - 1) / K1_NB;
        k_count8<<<K1_NB, 512, 0, stream>>>(src, nquads, qpbK1, sbsz, gcnt8);
        k_scan8<<<1, 64, 0, stream>>>(gcnt8, bbase8, gcur8);
        k_p1<<<P1_NB, P1_THR, 0, stream>>>(src, dst, ea, w_edge, b_edge,
                                           nquads, qpb1, sbsz, DB,
                                           gcur8, gcntD, recs);
        k_scanD<<<1, 64, 0, stream>>>(gcntD, DB, bbaseD, gcurD);
        const int cpb = (E + NSB * CH - 1) / (NSB * CH) + 64;  // grid-stride covers skew
        k_p2<<<NSB * cpb, P2_THR, 0, stream>>>(recs, x, bbase8, sbsz, DB, cpb,
                                               gcurD, pairs);
        k_binB<<<DB, 1024, 0, stream>>>(pairs, bbaseD, x, w_root, b_conv,
                                        nodes, N);
        head_kernel<<<hblocks, HEAD_BLK, 0, stream>>>(nodes, W1, b1, W2, b2,
                                                      W3, b3, out, G);
    } else if (quadok && need_mid <= ws_size) {
        unsigned* pairs = (unsigned*)ws;
        float*    nodes = (float*)(ws + off_nodes_mid);
        int*      meta  = (int*)(ws + off_meta_mid);
        int* gcnt8  = meta;
        int* gcntD  = meta + 8;
        int* bbase8 = meta + 8 + DBMAX;
        int* gcur8  = bbase8 + 9;
        int* bbaseD = gcur8 + 8;
        int* gcurD  = bbaseD + DBMAX + 1;
        (void)gcnt8; (void)bbase8; (void)gcur8;

        hipMemsetAsync(meta, 0, (8 + DBMAX) * sizeof(int), stream);
        const int NBm = 2048;
        const int qpbm = (nquads + NBm - 1) / NBm;
        k_count_mid<<<NBm, 512, 0, stream>>>(dst, nquads, qpbm, DB, gcntD);
        k_scanD<<<1, 64, 0, stream>>>(gcntD, DB, bbaseD, gcurD);
        k_binA_resv<<<NBm, 512, 0, stream>>>(x, src, dst, ea, w_edge, b_edge,
                                             nquads, qpbm, DB, gcurD, pairs);
        k_binB<<<DB, 1024, 0, stream>>>(pairs, bbaseD, x, w_root, b_conv,
                                        nodes, N);
        head_kernel<<<hblocks, HEAD_BLK, 0, stream>>>(nodes, W1, b1, W2, b2,
                                                      W3, b3, out, G);
    } else {
        float* agg   = (float*)d_ws;
        float* nodes = agg + N;
        hipMemsetAsync(agg, 0, (size_t)N * sizeof(float), stream);
        edge_kernel_atomic<<<2048, 256, 0, stream>>>(x, src, dst, ea, w_edge,
                                                     b_edge, agg, E);
        finalize_nodes<<<2048, 256, 0, stream>>>(x, agg, w_root, b_conv, nodes, N);
        head_kernel<<<hblocks, HEAD_BLK, 0, stream>>>(nodes, W1, b1, W2, b2,
                                                      W3, b3, out, G);
    }
}